// Round 8
// baseline (9495.244 us; speedup 1.0000x reference)
//
#include <hip/hip_runtime.h>
#include <cstdint>
#include <cstddef>

// Decoder (DA-RNN): B=512, T=256, E=D=256.
// Round 10: R6 base (verified best, 5040us k_scan) + ONE change: phase-3's
// Ph2 loads (the L3/HBM-latency stream) are issued as 16 named half8 SSA
// values at the TOP of phase 2 and consumed after B2 in phase 3.
//  - B2 pins the schedule (compiler cannot sink loads past __syncthreads)
//    and drains them: latency hides under the gates GEMV.
//  - plain loads (nontemporal dropped): Ph2 (64MB) should retain in L3.
//  - uniform across all 1024 threads (R7's divergent-role batches spilled);
//    intra-iteration liveness only (no loop-carry): +32 VGPR transient.
// Canaries: VGPR ~90-112, WRITE_SIZE ~KB. Everything else identical to R6.

typedef _Float16 half8 __attribute__((ext_vector_type(8)));
typedef _Float16 half4v __attribute__((ext_vector_type(4)));
typedef _Float16 half2v __attribute__((ext_vector_type(2)));

__device__ __forceinline__ float rcpf_(float x) { return __builtin_amdgcn_rcpf(x); }
__device__ __forceinline__ float sigmoidf_(float x) { return rcpf_(1.f + __expf(-x)); }
__device__ __forceinline__ float tanhf_(float x) { return 1.f - 2.f * rcpf_(1.f + __expf(2.f * x)); }

#if defined(__has_builtin)
#if __has_builtin(__builtin_amdgcn_fdot2)
#define HAS_FDOT2 1
#endif
#endif
#ifndef HAS_FDOT2
#define HAS_FDOT2 0
#endif

__device__ __forceinline__ float fdot2_(half2v a, half2v b, float c) {
#if HAS_FDOT2
  return __builtin_amdgcn_fdot2(a, b, c, false);
#else
  return fmaf((float)a[0], (float)b[0], fmaf((float)a[1], (float)b[1], c));
#endif
}

__device__ __forceinline__ float dot8_(half8 w, half8 h, float acc) {
  acc = fdot2_(__builtin_shufflevector(w, w, 0, 1), __builtin_shufflevector(h, h, 0, 1), acc);
  acc = fdot2_(__builtin_shufflevector(w, w, 2, 3), __builtin_shufflevector(h, h, 2, 3), acc);
  acc = fdot2_(__builtin_shufflevector(w, w, 4, 5), __builtin_shufflevector(h, h, 4, 5), acc);
  acc = fdot2_(__builtin_shufflevector(w, w, 6, 7), __builtin_shufflevector(h, h, 6, 7), acc);
  return acc;
}

// ---------------- prep kernels ----------------

// wT[e*256+f] = attn_w1[f*768 + 512 + e]   (transposed w1_enc, fp32)
__global__ void k_prep_wT(const float* __restrict__ w1, float* __restrict__ wT) {
  int id = blockIdx.x * 256 + threadIdx.x;
  int e = id >> 8, f = id & 255;
  wT[id] = w1[f * 768 + 512 + e];
}

// x -> fp16 (4 elems/thread), layout unchanged [b][t][e]
__global__ void k_prep_xh(const float* __restrict__ x, _Float16* __restrict__ xh) {
  int id = blockIdx.x * 256 + threadIdx.x;
  float4 v = reinterpret_cast<const float4*>(x)[id];
  half4v h;
  h[0] = (_Float16)v.x; h[1] = (_Float16)v.y; h[2] = (_Float16)v.z; h[3] = (_Float16)v.w;
  reinterpret_cast<half4v*>(xh)[id] = h;
}

// w1hcQ[(c*1024 + t)*8 + m] = w1[e*768 + k],  t = jk*256 + e  (jk = t>>8
// wave-uniform in k_scan), k = jk*128 + c*8 + m, c in [0,16)
__global__ void k_prep_w1hcQ(const float* __restrict__ w1, _Float16* __restrict__ o) {
  int id = blockIdx.x * 256 + threadIdx.x;  // 131072 total
  int m = id & 7, t = (id >> 3) & 1023, c = id >> 13;
  int e = t & 255, jk = t >> 8;
  int k = jk * 128 + c * 8 + m;
  o[id] = (_Float16)w1[e * 768 + k];
}

// whhG[(((jk*8 + c)*4 + jslot)*256 + jo)*8 + m] = Whh[(jslot*256+jo)*256 + jk*64 + c*8 + m]
// (thread (jo, jk=tid>>8) computes 4 outputs jslot*256+jo over k in [jk*64,+64))
__global__ void k_prep_whhG(const float* __restrict__ whh, _Float16* __restrict__ o) {
  int id = blockIdx.x * 256 + threadIdx.x;  // 262144 total
  int m = id & 7, jo = (id >> 3) & 255, jslot = (id >> 11) & 3;
  int c = (id >> 13) & 7, jk = id >> 16;
  int j = jslot * 256 + jo, k = jk * 64 + c * 8 + m;
  o[id] = (_Float16)whh[j * 256 + k];
}

// xf[b*256+t] = sum_e x[b,t,e] * fcw[e]   (fp32)
__global__ __launch_bounds__(256) void k_xf(const float* __restrict__ x,
                                            const float* __restrict__ fcw,
                                            float* __restrict__ xf) {
  __shared__ float xl[16][256];
  __shared__ float fw[256];
  __shared__ float part[16][17];
  const int tid = threadIdx.x;
  const int m0 = blockIdx.x * 16;
  fw[tid] = fcw[tid];
#pragma unroll
  for (int r = 0; r < 16; ++r) xl[r][tid] = x[(size_t)(m0 + r) * 256 + tid];
  __syncthreads();
  int r = tid >> 4, p = tid & 15;
  float s = 0.f;
#pragma unroll
  for (int u = 0; u < 16; ++u) s = fmaf(xl[r][p * 16 + u], fw[p * 16 + u], s);
  part[r][p] = s;
  __syncthreads();
  if (tid < 16) {
    float t = 0.f;
#pragma unroll
    for (int p2 = 0; p2 < 16; ++p2) t += part[tid][p2];
    xf[m0 + tid] = t;
  }
}

// enc_proj GEMM + bias, store P=exp(2*encp) fp16 in layout [b][e/8][t][e%8]
__global__ __launch_bounds__(256) void k_encp(const float* __restrict__ x,
                                              const float* __restrict__ wT,
                                              const float* __restrict__ b1,
                                              _Float16* __restrict__ Ph2) {
  __shared__ __align__(16) float xl[16][256];
  const int tid = threadIdx.x;
  const int m0 = blockIdx.x * 16;
#pragma unroll
  for (int r = 0; r < 16; ++r) xl[r][tid] = x[(size_t)(m0 + r) * 256 + tid];
  __syncthreads();
  float acc[16];
#pragma unroll
  for (int r = 0; r < 16; ++r) acc[r] = 0.f;
  for (int e = 0; e < 256; e += 4) {
    float w0 = wT[(e + 0) * 256 + tid];
    float w1_ = wT[(e + 1) * 256 + tid];
    float w2_ = wT[(e + 2) * 256 + tid];
    float w3_ = wT[(e + 3) * 256 + tid];
#pragma unroll
    for (int r = 0; r < 16; ++r) {
      float4 xv = *reinterpret_cast<const float4*>(&xl[r][e]);
      acc[r] = fmaf(xv.x, w0, acc[r]);
      acc[r] = fmaf(xv.y, w1_, acc[r]);
      acc[r] = fmaf(xv.z, w2_, acc[r]);
      acc[r] = fmaf(xv.w, w3_, acc[r]);
    }
  }
  float bb = b1[tid];
  const int e = tid;
#pragma unroll
  for (int r = 0; r < 16; ++r) {
    int m = m0 + r, b = m >> 8, t = m & 255;
    float p = __expf(2.f * (acc[r] + bb));
    Ph2[((size_t)(b * 32 + (e >> 3)) * 256 + t) * 8 + (e & 7)] = (_Float16)p;
  }
}

#define SC1(pv, c) { \
  float4 qa = q4[2*(c)], wa = w4[2*(c)]; \
  sacc0 = fmaf(wa.x, rcpf_(fmaf((float)pv[0], qa.x, 1.f)), sacc0); \
  sacc1 = fmaf(wa.y, rcpf_(fmaf((float)pv[1], qa.y, 1.f)), sacc1); \
  sacc0 = fmaf(wa.z, rcpf_(fmaf((float)pv[2], qa.z, 1.f)), sacc0); \
  sacc1 = fmaf(wa.w, rcpf_(fmaf((float)pv[3], qa.w, 1.f)), sacc1); \
  float4 qb = q4[2*(c)+1], wb = w4[2*(c)+1]; \
  sacc0 = fmaf(wb.x, rcpf_(fmaf((float)pv[4], qb.x, 1.f)), sacc0); \
  sacc1 = fmaf(wb.y, rcpf_(fmaf((float)pv[5], qb.y, 1.f)), sacc1); \
  sacc0 = fmaf(wb.z, rcpf_(fmaf((float)pv[6], qb.z, 1.f)), sacc0); \
  sacc1 = fmaf(wb.w, rcpf_(fmaf((float)pv[7], qb.w, 1.f)), sacc1); }

// ---------------- the scan ----------------
// grid 256 x 1024 threads; wg owns 2 batch rows; 256 steps; 16 waves/CU.
__global__ __launch_bounds__(1024, 4) void k_scan(
    const _Float16* __restrict__ Ph2, const _Float16* __restrict__ xh,
    const _Float16* __restrict__ w1hcQ, const _Float16* __restrict__ whhG,
    const float* __restrict__ xf, const float* __restrict__ y_hist,
    const float* __restrict__ w2g, const float* __restrict__ Wih,
    const float* __restrict__ bih, const float* __restrict__ bhh,
    const float* __restrict__ fcw, const float* __restrict__ fcb,
    const float* __restrict__ fcfw, const float* __restrict__ fcfb,
    float* __restrict__ out) {
  __shared__ __align__(16) float hc[2][512];        // fp32 [g][ h | c ]
  __shared__ __align__(16) _Float16 hcH[2][512];    // fp16 mirror for dot2
  __shared__ __align__(16) float qpart[4][2][256];  // [jk][g][e]
  __shared__ __align__(16) float Qs[2][256];        // exp(2q)
  __shared__ __align__(16) float spart[2][2][256];  // [eh][g][t]
  __shared__ __align__(16) float ealpha[2][256];
  __shared__ __align__(16) float gpart[4][2][1024]; // [jk][g][j]; aliased post-loop as cpart[2][16][256]
  __shared__ __align__(16) float w2l[256];
  __shared__ __align__(16) float Wihl[1024];
  __shared__ __align__(16) float bl[1024];
  __shared__ __align__(16) float xfL[2][256];
  __shared__ __align__(16) float yhL[2][256];
  __shared__ float redA[8], redB[8];

  const int tid = threadIdx.x;
  const int b0 = blockIdx.x * 2;
  const int hi = tid >> 8;     // 0..3, wave-uniform
  const int lo = tid & 255;
  const int wv = tid >> 6, lane = tid & 63;

  // ---- init ----
  ((float*)hc)[tid] = 0.f;
  ((_Float16*)hcH)[tid] = (_Float16)0.f;
  if (tid < 256) w2l[tid] = w2g[tid];
  Wihl[tid & 1023] = Wih[tid & 1023];
  bl[tid] = bih[tid] + bhh[tid];
  if (tid < 512) {
    int gi = tid >> 8, ti = tid & 255;
    xfL[gi][ti] = xf[(size_t)(b0 + gi) * 256 + ti];
    yhL[gi][ti] = y_hist[(size_t)(b0 + gi) * 256 + ti];
  }
  __syncthreads();
  float w2sum = 0.f;
  for (int e2 = 0; e2 < 256; ++e2) w2sum += w2l[e2];
  const float fcb0 = fcb[0];
  const float fcwy = fcw[256];

  // per-thread role constants
  // q phase: thread = (jk = hi, e = lo), k in [jk*128, +128)  [wave-uniform jk]
  const half8* wq = reinterpret_cast<const half8*>(w1hcQ) + tid;  // chunk c: wq[c*1024]
  // gates: thread = (jo = lo, jk = hi); outputs jslot*256+jo, k in [jk*64, +64)
  const half8* wg = reinterpret_cast<const half8*>(whhG) + (size_t)hi * 8192 + lo;
  // scores: thread = (g = tid>>9, eh = (tid>>8)&1, t = lo), e in [eh*128, +128)
  const int gs = tid >> 9, eh = (tid >> 8) & 1;
  const half8* prow = reinterpret_cast<const half8*>(Ph2) +
                      ((size_t)((b0 + gs) * 32 + eh * 16)) * 256 + lo;
  // pointwise / softmax-combine (tid < 512)
  const int gp = (tid >> 8) & 1;

#pragma unroll 1
  for (int s = 0; s < 256; ++s) {
    // ---- phase 1: q[e] = hc . w1_hc[e,:], k-split 4 (wave-uniform), both rows ----
    float a0 = 0.f, a1 = 0.f;
    {
      const half8* hp0 = reinterpret_cast<const half8*>(&hcH[0][hi * 128]);
      const half8* hp1 = reinterpret_cast<const half8*>(&hcH[1][hi * 128]);
#pragma unroll 8
      for (int c = 0; c < 16; ++c) {
        half8 w = wq[c * 1024];
        half8 h0 = hp0[c];   // broadcast read (same addr across wave)
        half8 h1 = hp1[c];
        a0 = dot8_(w, h0, a0);
        a1 = dot8_(w, h1, a1);
      }
    }
    qpart[hi][0][lo] = a0;
    qpart[hi][1][lo] = a1;
    __syncthreads();  // B1

    // ---- phase 2: Ph2 prefetch (issue first!) + Qs + gates GEMV ----
    // 16 plain loads issued at phase top; B2 pins + drains them; consumed in
    // phase 3 from registers. Latency hides under the gates GEMV below.
    half8 ph0 = prow[0 * 256];
    half8 ph1 = prow[1 * 256];
    half8 ph2 = prow[2 * 256];
    half8 ph3 = prow[3 * 256];
    half8 ph4 = prow[4 * 256];
    half8 ph5 = prow[5 * 256];
    half8 ph6 = prow[6 * 256];
    half8 ph7 = prow[7 * 256];
    half8 ph8 = prow[8 * 256];
    half8 ph9 = prow[9 * 256];
    half8 ph10 = prow[10 * 256];
    half8 ph11 = prow[11 * 256];
    half8 ph12 = prow[12 * 256];
    half8 ph13 = prow[13 * 256];
    half8 ph14 = prow[14 * 256];
    half8 ph15 = prow[15 * 256];

    if (tid < 512) {
      float qv = qpart[0][gp][lo] + qpart[1][gp][lo] + qpart[2][gp][lo] + qpart[3][gp][lo];
      Qs[gp][lo] = __expf(2.f * qv);
    }
    float ac0[4], ac1[4];
#pragma unroll
    for (int m = 0; m < 4; ++m) { ac0[m] = 0.f; ac1[m] = 0.f; }
    {
      const half8* hg0 = reinterpret_cast<const half8*>(&hcH[0][hi * 64]);
      const half8* hg1 = reinterpret_cast<const half8*>(&hcH[1][hi * 64]);
#pragma unroll 2
      for (int c = 0; c < 8; ++c) {
        half8 h0 = hg0[c];   // broadcast
        half8 h1 = hg1[c];
#pragma unroll
        for (int jslot = 0; jslot < 4; ++jslot) {
          half8 w = wg[(c * 4 + jslot) * 256];
          ac0[jslot] = dot8_(w, h0, ac0[jslot]);
          ac1[jslot] = dot8_(w, h1, ac1[jslot]);
        }
      }
    }
#pragma unroll
    for (int jslot = 0; jslot < 4; ++jslot) {
      gpart[hi][0][jslot * 256 + lo] = ac0[jslot];
      gpart[hi][1][jslot * 256 + lo] = ac1[jslot];
    }
    __syncthreads();  // B2  (drains the ph* loads)

    // ---- phase 3: scores from registers, e-split 2 ----
    float sacc0 = 0.f, sacc1 = 0.f;
    {
      const float4* q4 = reinterpret_cast<const float4*>(&Qs[gs][eh * 128]);
      const float4* w4 = reinterpret_cast<const float4*>(&w2l[eh * 128]);
      SC1(ph0, 0)  SC1(ph1, 1)  SC1(ph2, 2)  SC1(ph3, 3)
      SC1(ph4, 4)  SC1(ph5, 5)  SC1(ph6, 6)  SC1(ph7, 7)
      SC1(ph8, 8)  SC1(ph9, 9)  SC1(ph10, 10) SC1(ph11, 11)
      SC1(ph12, 12) SC1(ph13, 13) SC1(ph14, 14) SC1(ph15, 15)
    }
    spart[eh][gs][lo] = sacc0 + sacc1;
    __syncthreads();  // B3

    // ---- phase 4: combine + softmax reduce (tid < 512) ----
    if (tid < 512) {
      float sc = w2sum - 2.f * (spart[0][gp][lo] + spart[1][gp][lo]);
      float ea = __expf(sc);  // no max-sub: |sc| <= ~21, fp32-safe
      ealpha[gp][lo] = ea;
      float ef = ea * xfL[gp][lo];
      float es = ea;
#pragma unroll
      for (int off = 32; off > 0; off >>= 1) {
        es += __shfl_xor(es, off);
        ef += __shfl_xor(ef, off);
      }
      if (lane == 0) { redA[wv] = es; redB[wv] = ef; }
    }
    __syncthreads();  // B4

    // ---- phase 5: LSTM pointwise (tid < 512) ----
    if (tid < 512) {
      float es = (gp == 0) ? (redA[0] + redA[1] + redA[2] + redA[3])
                           : (redA[4] + redA[5] + redA[6] + redA[7]);
      float ef = (gp == 0) ? (redB[0] + redB[1] + redB[2] + redB[3])
                           : (redB[4] + redB[5] + redB[6] + redB[7]);
      float yt = ef * rcpf_(es) + fmaf(yhL[gp][s], fcwy, fcb0);
      float gi = fmaf(yt, Wihl[lo], bl[lo]);
      float gf = fmaf(yt, Wihl[256 + lo], bl[256 + lo]);
      float gc = fmaf(yt, Wihl[512 + lo], bl[512 + lo]);
      float go = fmaf(yt, Wihl[768 + lo], bl[768 + lo]);
#pragma unroll
      for (int q2 = 0; q2 < 4; ++q2) {
        gi += gpart[q2][gp][lo];
        gf += gpart[q2][gp][256 + lo];
        gc += gpart[q2][gp][512 + lo];
        go += gpart[q2][gp][768 + lo];
      }
      float iv = sigmoidf_(gi), fv = sigmoidf_(gf), gv = tanhf_(gc), ov = sigmoidf_(go);
      float cold = hc[gp][256 + lo];
      float cn = fmaf(fv, cold, iv * gv);
      float hn = ov * tanhf_(cn);
      hc[gp][lo] = hn;
      hc[gp][256 + lo] = cn;
      hcH[gp][lo] = (_Float16)hn;
      hcH[gp][256 + lo] = (_Float16)cn;
    }
    __syncthreads();  // B5
  }

  // ---- epilogue: context from step-255 ealpha, then out = [h|ctx].fcf ----
  // read last-step softmax sums BEFORE redA/redB get reused
  const float rsA = rcpf_(redA[0] + redA[1] + redA[2] + redA[3]);
  const float rsB = rcpf_(redA[4] + redA[5] + redA[6] + redA[7]);

  float* cpartF = &gpart[0][0][0];  // alias: cpart[g][u][t] = cpartF[(g*16+u)*256+t]
  {
    const int gc = tid >> 9, t16 = (tid >> 5) & 15, l5 = tid & 31;
    const half8* xrow = reinterpret_cast<const half8*>(xh) +
                        ((size_t)(b0 + gc) * 256 + t16 * 16) * 32 + l5;
    float acx[8];
#pragma unroll
    for (int m = 0; m < 8; ++m) acx[m] = 0.f;
#pragma unroll 4
    for (int it = 0; it < 16; ++it) {
      float al = ealpha[gc][t16 * 16 + it];
      half8 xv = xrow[it * 32];
#pragma unroll
      for (int m = 0; m < 8; ++m) acx[m] = fmaf(al, (float)xv[m], acx[m]);
    }
    float* dst = &cpartF[((gc * 16 + t16) * 256) + l5 * 8];
    *reinterpret_cast<float4*>(dst) = *reinterpret_cast<float4*>(&acx[0]);
    *reinterpret_cast<float4*>(dst + 4) = *reinterpret_cast<float4*>(&acx[4]);
  }
  __syncthreads();

  if (tid < 512) {
    float cv = 0.f;
#pragma unroll
    for (int u = 0; u < 16; ++u) cv += cpartF[((gp * 16 + u) * 256) + lo];
    cv *= (gp == 0) ? rsA : rsB;
    float hval = hc[gp][lo];
    float p0 = hval * fcfw[lo] + cv * fcfw[256 + lo];
    float p1 = hval * fcfw[512 + lo] + cv * fcfw[768 + lo];
#pragma unroll
    for (int off = 32; off > 0; off >>= 1) {
      p0 += __shfl_xor(p0, off);
      p1 += __shfl_xor(p1, off);
    }
    if (lane == 0) { redA[wv] = p0; redB[wv] = p1; }
  }
  __syncthreads();
  if (tid < 4) {
    int g2 = tid >> 1, o = tid & 1;
    const float* r = (o == 0) ? redA : redB;
    float v = fcfb[o] + r[g2 * 4 + 0] + r[g2 * 4 + 1] + r[g2 * 4 + 2] + r[g2 * 4 + 3];
    out[(b0 + g2) * 2 + o] = v;
  }
}

extern "C" void kernel_launch(void* const* d_in, const int* in_sizes, int n_in,
                              void* d_out, int out_size, void* d_ws, size_t ws_size,
                              hipStream_t stream) {
  (void)in_sizes; (void)n_in; (void)out_size; (void)ws_size;
  const float* x    = (const float*)d_in[0];
  const float* yh   = (const float*)d_in[1];
  const float* w1   = (const float*)d_in[2];
  const float* b1   = (const float*)d_in[3];
  const float* w2   = (const float*)d_in[4];
  /* d_in[5] attn_b2: softmax-invariant, unused */
  const float* Wih  = (const float*)d_in[6];
  const float* Whh  = (const float*)d_in[7];
  const float* bih  = (const float*)d_in[8];
  const float* bhh  = (const float*)d_in[9];
  const float* fcw  = (const float*)d_in[10];
  const float* fcb  = (const float*)d_in[11];
  const float* fcfw = (const float*)d_in[12];
  const float* fcfb = (const float*)d_in[13];
  float* out = (float*)d_out;

  char* ws = (char*)d_ws;
  _Float16* Ph2   = (_Float16*)(ws);                      // 67108864 B
  _Float16* xh    = (_Float16*)(ws + (size_t)67108864);   // 67108864 B
  float*    wT    = (float*)   (ws + (size_t)134217728);  // 262144 B
  _Float16* w1hcQ = (_Float16*)(ws + (size_t)134479872);  // 262144 B
  _Float16* whhG  = (_Float16*)(ws + (size_t)134742016);  // 524288 B
  float*    xf    = (float*)   (ws + (size_t)135266304);  // 524288 B
  // total: 135790592 B (~129.5 MB)

  k_prep_wT   <<<256,   256, 0, stream>>>(w1, wT);
  k_prep_xh   <<<32768, 256, 0, stream>>>(x, xh);
  k_prep_w1hcQ<<<512,   256, 0, stream>>>(w1, w1hcQ);
  k_prep_whhG <<<1024,  256, 0, stream>>>(Whh, whhG);
  k_xf        <<<8192,  256, 0, stream>>>(x, fcw, xf);
  k_encp      <<<8192,  256, 0, stream>>>(x, wT, b1, Ph2);
  k_scan      <<<256,  1024, 0, stream>>>(Ph2, xh, w1hcQ, whhG, xf, yh, w2, Wih,
                                          bih, bhh, fcw, fcb, fcfw, fcfb, out);
}

// Round 9
// 6447.387 us; speedup vs baseline: 1.4727x; 1.4727x over previous
//
#include <hip/hip_runtime.h>
#include <cstdint>
#include <cstddef>

// Decoder (DA-RNN): B=512, T=256, E=D=256.
// Round 11: stream overlap via PHASE CONCURRENCY (no cross-barrier registers --
// R8/R7/R5/R4 all proved any named-register state crossing __syncthreads gets
// spilled by this allocator). Base = R6 (verified best, 5040us k_scan).
// Step restructured 5 phases -> 3:
//  P1: 256 threads compute q FULL-k (both rows) -> write Qs=exp(2q) directly
//      (kills qpart round-trip + combine barrier).
//  P2: tid<512 gates GEMV (whh, L2 stream) CONCURRENT WITH tid>=512 scores
//      (full e-range, Ph2 L3 stream) + ealpha + wave reduce -> redA/redB.
//      The two fat streams (L2 whh / L3 Ph2) now overlap instead of
//      serializing across a barrier. (kills spart + combine barrier)
//  P3: tid<512 LSTM pointwise.
// 3 barriers/step (was 5). All LDS h/Q/w2 reads remain wave-uniform
// broadcasts; all partial writes lane-consecutive (R6's conflict fix).

typedef _Float16 half8 __attribute__((ext_vector_type(8)));
typedef _Float16 half4v __attribute__((ext_vector_type(4)));
typedef _Float16 half2v __attribute__((ext_vector_type(2)));

__device__ __forceinline__ float rcpf_(float x) { return __builtin_amdgcn_rcpf(x); }
__device__ __forceinline__ float sigmoidf_(float x) { return rcpf_(1.f + __expf(-x)); }
__device__ __forceinline__ float tanhf_(float x) { return 1.f - 2.f * rcpf_(1.f + __expf(2.f * x)); }

#if defined(__has_builtin)
#if __has_builtin(__builtin_amdgcn_fdot2)
#define HAS_FDOT2 1
#endif
#endif
#ifndef HAS_FDOT2
#define HAS_FDOT2 0
#endif

__device__ __forceinline__ float fdot2_(half2v a, half2v b, float c) {
#if HAS_FDOT2
  return __builtin_amdgcn_fdot2(a, b, c, false);
#else
  return fmaf((float)a[0], (float)b[0], fmaf((float)a[1], (float)b[1], c));
#endif
}

__device__ __forceinline__ float dot8_(half8 w, half8 h, float acc) {
  acc = fdot2_(__builtin_shufflevector(w, w, 0, 1), __builtin_shufflevector(h, h, 0, 1), acc);
  acc = fdot2_(__builtin_shufflevector(w, w, 2, 3), __builtin_shufflevector(h, h, 2, 3), acc);
  acc = fdot2_(__builtin_shufflevector(w, w, 4, 5), __builtin_shufflevector(h, h, 4, 5), acc);
  acc = fdot2_(__builtin_shufflevector(w, w, 6, 7), __builtin_shufflevector(h, h, 6, 7), acc);
  return acc;
}

// ---------------- prep kernels ----------------

// wT[e*256+f] = attn_w1[f*768 + 512 + e]   (transposed w1_enc, fp32)
__global__ void k_prep_wT(const float* __restrict__ w1, float* __restrict__ wT) {
  int id = blockIdx.x * 256 + threadIdx.x;
  int e = id >> 8, f = id & 255;
  wT[id] = w1[f * 768 + 512 + e];
}

// x -> fp16 (4 elems/thread), layout unchanged [b][t][e]
__global__ void k_prep_xh(const float* __restrict__ x, _Float16* __restrict__ xh) {
  int id = blockIdx.x * 256 + threadIdx.x;
  float4 v = reinterpret_cast<const float4*>(x)[id];
  half4v h;
  h[0] = (_Float16)v.x; h[1] = (_Float16)v.y; h[2] = (_Float16)v.z; h[3] = (_Float16)v.w;
  reinterpret_cast<half4v*>(xh)[id] = h;
}

// w1hcF[(c*256 + e)*8 + m] = w1[e*768 + c*8 + m], c in [0,64)  (full-k q rows)
// k_scan q-thread e reads chunk c at half8 index c*256+e (lane-consecutive).
__global__ void k_prep_w1hcQ(const float* __restrict__ w1, _Float16* __restrict__ o) {
  int id = blockIdx.x * 256 + threadIdx.x;  // 131072 total
  int m = id & 7, e = (id >> 3) & 255, c = id >> 11;
  o[id] = (_Float16)w1[e * 768 + c * 8 + m];
}

// whhG[(((kh*16 + c)*4 + js)*256 + jo)*8 + m] = Whh[(js*256+jo)*256 + kh*128 + c*8 + m]
// (gate thread (jo, kh) computes outputs js*256+jo over k in [kh*128,+128))
__global__ void k_prep_whhG(const float* __restrict__ whh, _Float16* __restrict__ o) {
  int id = blockIdx.x * 256 + threadIdx.x;  // 262144 total
  int m = id & 7, jo = (id >> 3) & 255, js = (id >> 11) & 3;
  int c = (id >> 13) & 15, kh = id >> 17;
  int j = js * 256 + jo, k = kh * 128 + c * 8 + m;
  o[id] = (_Float16)whh[j * 256 + k];
}

// xf[b*256+t] = sum_e x[b,t,e] * fcw[e]   (fp32)
__global__ __launch_bounds__(256) void k_xf(const float* __restrict__ x,
                                            const float* __restrict__ fcw,
                                            float* __restrict__ xf) {
  __shared__ float xl[16][256];
  __shared__ float fw[256];
  __shared__ float part[16][17];
  const int tid = threadIdx.x;
  const int m0 = blockIdx.x * 16;
  fw[tid] = fcw[tid];
#pragma unroll
  for (int r = 0; r < 16; ++r) xl[r][tid] = x[(size_t)(m0 + r) * 256 + tid];
  __syncthreads();
  int r = tid >> 4, p = tid & 15;
  float s = 0.f;
#pragma unroll
  for (int u = 0; u < 16; ++u) s = fmaf(xl[r][p * 16 + u], fw[p * 16 + u], s);
  part[r][p] = s;
  __syncthreads();
  if (tid < 16) {
    float t = 0.f;
#pragma unroll
    for (int p2 = 0; p2 < 16; ++p2) t += part[tid][p2];
    xf[m0 + tid] = t;
  }
}

// enc_proj GEMM + bias, store P=exp(2*encp) fp16 in layout [b][e/8][t][e%8]
__global__ __launch_bounds__(256) void k_encp(const float* __restrict__ x,
                                              const float* __restrict__ wT,
                                              const float* __restrict__ b1,
                                              _Float16* __restrict__ Ph2) {
  __shared__ __align__(16) float xl[16][256];
  const int tid = threadIdx.x;
  const int m0 = blockIdx.x * 16;
#pragma unroll
  for (int r = 0; r < 16; ++r) xl[r][tid] = x[(size_t)(m0 + r) * 256 + tid];
  __syncthreads();
  float acc[16];
#pragma unroll
  for (int r = 0; r < 16; ++r) acc[r] = 0.f;
  for (int e = 0; e < 256; e += 4) {
    float w0 = wT[(e + 0) * 256 + tid];
    float w1_ = wT[(e + 1) * 256 + tid];
    float w2_ = wT[(e + 2) * 256 + tid];
    float w3_ = wT[(e + 3) * 256 + tid];
#pragma unroll
    for (int r = 0; r < 16; ++r) {
      float4 xv = *reinterpret_cast<const float4*>(&xl[r][e]);
      acc[r] = fmaf(xv.x, w0, acc[r]);
      acc[r] = fmaf(xv.y, w1_, acc[r]);
      acc[r] = fmaf(xv.z, w2_, acc[r]);
      acc[r] = fmaf(xv.w, w3_, acc[r]);
    }
  }
  float bb = b1[tid];
  const int e = tid;
#pragma unroll
  for (int r = 0; r < 16; ++r) {
    int m = m0 + r, b = m >> 8, t = m & 255;
    float p = __expf(2.f * (acc[r] + bb));
    Ph2[((size_t)(b * 32 + (e >> 3)) * 256 + t) * 8 + (e & 7)] = (_Float16)p;
  }
}

#define SC1(pv, c) { \
  float4 qa = q4[2*(c)], wa = w4[2*(c)]; \
  sacc0 = fmaf(wa.x, rcpf_(fmaf((float)pv[0], qa.x, 1.f)), sacc0); \
  sacc1 = fmaf(wa.y, rcpf_(fmaf((float)pv[1], qa.y, 1.f)), sacc1); \
  sacc0 = fmaf(wa.z, rcpf_(fmaf((float)pv[2], qa.z, 1.f)), sacc0); \
  sacc1 = fmaf(wa.w, rcpf_(fmaf((float)pv[3], qa.w, 1.f)), sacc1); \
  float4 qb = q4[2*(c)+1], wb = w4[2*(c)+1]; \
  sacc0 = fmaf(wb.x, rcpf_(fmaf((float)pv[4], qb.x, 1.f)), sacc0); \
  sacc1 = fmaf(wb.y, rcpf_(fmaf((float)pv[5], qb.y, 1.f)), sacc1); \
  sacc0 = fmaf(wb.z, rcpf_(fmaf((float)pv[6], qb.z, 1.f)), sacc0); \
  sacc1 = fmaf(wb.w, rcpf_(fmaf((float)pv[7], qb.w, 1.f)), sacc1); }

// ---------------- the scan ----------------
// grid 256 x 1024 threads; wg owns 2 batch rows; 256 steps; 3 barriers/step.
__global__ __launch_bounds__(1024, 4) void k_scan(
    const _Float16* __restrict__ Ph2, const _Float16* __restrict__ xh,
    const _Float16* __restrict__ w1hcQ, const _Float16* __restrict__ whhG,
    const float* __restrict__ xf, const float* __restrict__ y_hist,
    const float* __restrict__ w2g, const float* __restrict__ Wih,
    const float* __restrict__ bih, const float* __restrict__ bhh,
    const float* __restrict__ fcw, const float* __restrict__ fcb,
    const float* __restrict__ fcfw, const float* __restrict__ fcfb,
    float* __restrict__ out) {
  __shared__ __align__(16) float hc[2][512];        // fp32 [g][ h | c ]
  __shared__ __align__(16) _Float16 hcH[2][512];    // fp16 mirror for dot2
  __shared__ __align__(16) float Qs[2][256];        // exp(2q)
  __shared__ __align__(16) float ealpha[2][256];
  __shared__ __align__(16) float gpart[4][2][1024]; // [kh 0..1 used][g][j]; full size kept as epilogue cpart alias (32KB)
  __shared__ __align__(16) float w2l[256];
  __shared__ __align__(16) float Wihl[1024];
  __shared__ __align__(16) float bl[1024];
  __shared__ __align__(16) float xfL[2][256];
  __shared__ __align__(16) float yhL[2][256];
  __shared__ float redA[16], redB[16];

  const int tid = threadIdx.x;
  const int b0 = blockIdx.x * 2;
  const int lo = tid & 255;
  const int wv = tid >> 6, lane = tid & 63;

  // ---- init ----
  ((float*)hc)[tid] = 0.f;
  ((_Float16*)hcH)[tid] = (_Float16)0.f;
  if (tid < 256) w2l[tid] = w2g[tid];
  Wihl[tid] = Wih[tid];
  bl[tid] = bih[tid] + bhh[tid];
  if (tid < 512) {
    int gi = tid >> 8, ti = tid & 255;
    xfL[gi][ti] = xf[(size_t)(b0 + gi) * 256 + ti];
    yhL[gi][ti] = y_hist[(size_t)(b0 + gi) * 256 + ti];
  }
  __syncthreads();
  float w2sum = 0.f;
  for (int e2 = 0; e2 < 256; ++e2) w2sum += w2l[e2];
  const float fcb0 = fcb[0];
  const float fcwy = fcw[256];

  // ---- role constants ----
  // P1 q (tid<256): e = tid, full k=512, both rows
  const half8* wqF = reinterpret_cast<const half8*>(w1hcQ) + tid;   // [c*256], c<64
  // P2 gates (tid<512): jo = lo, kh = (tid>>8)&1; outputs js*256+jo, k in [kh*128,+128)
  const int kh = (tid >> 8) & 1;
  const half8* wg = reinterpret_cast<const half8*>(whhG) + kh * 16384 + lo;
  // P2 scores (tid>=512): gs = (tid>>8)&1, t = lo, full e-range
  const int gs = (tid >> 8) & 1;
  const half8* prow = reinterpret_cast<const half8*>(Ph2) +
                      ((size_t)((b0 + gs) * 32)) * 256 + lo;
  // P3 pointwise (tid<512): gp
  const int gp = (tid >> 8) & 1;

#pragma unroll 1
  for (int s = 0; s < 256; ++s) {
    // ---- P1: q full-k (both rows) -> Qs, by 256 threads ----
    if (tid < 256) {
      float a0 = 0.f, a1 = 0.f;
      const half8* hp0 = reinterpret_cast<const half8*>(&hcH[0][0]);
      const half8* hp1 = reinterpret_cast<const half8*>(&hcH[1][0]);
#pragma unroll 8
      for (int c = 0; c < 64; ++c) {
        half8 w = wqF[c * 256];
        a0 = dot8_(w, hp0[c], a0);   // broadcast LDS reads
        a1 = dot8_(w, hp1[c], a1);
      }
      Qs[0][tid] = __expf(2.f * a0);
      Qs[1][tid] = __expf(2.f * a1);
    }
    __syncthreads();  // B1

    // ---- P2: gates (tid<512, whh L2 stream) || scores (tid>=512, Ph2 L3 stream) ----
    if (tid < 512) {
      float ac0[4], ac1[4];
#pragma unroll
      for (int m = 0; m < 4; ++m) { ac0[m] = 0.f; ac1[m] = 0.f; }
      const half8* hg0 = reinterpret_cast<const half8*>(&hcH[0][kh * 128]);
      const half8* hg1 = reinterpret_cast<const half8*>(&hcH[1][kh * 128]);
#pragma unroll 4
      for (int c = 0; c < 16; ++c) {
        half8 h0 = hg0[c];   // broadcast
        half8 h1 = hg1[c];
#pragma unroll
        for (int js = 0; js < 4; ++js) {
          half8 w = wg[(c * 4 + js) * 256];
          ac0[js] = dot8_(w, h0, ac0[js]);
          ac1[js] = dot8_(w, h1, ac1[js]);
        }
      }
#pragma unroll
      for (int js = 0; js < 4; ++js) {
        gpart[kh][0][js * 256 + lo] = ac0[js];
        gpart[kh][1][js * 256 + lo] = ac1[js];
      }
    } else {
      float sacc0 = 0.f, sacc1 = 0.f;
      const float4* q4 = reinterpret_cast<const float4*>(&Qs[gs][0]);
      const float4* w4 = reinterpret_cast<const float4*>(&w2l[0]);
#pragma unroll 8
      for (int c = 0; c < 32; ++c) {
        half8 pv = __builtin_nontemporal_load(prow + c * 256);
        SC1(pv, c)
      }
      float sc = w2sum - 2.f * (sacc0 + sacc1);
      float ea = __expf(sc);  // no max-sub: |sc| <= ~21, fp32-safe
      ealpha[gs][lo] = ea;
      float ef = ea * xfL[gs][lo];
      float es = ea;
#pragma unroll
      for (int off = 32; off > 0; off >>= 1) {
        es += __shfl_xor(es, off);
        ef += __shfl_xor(ef, off);
      }
      if (lane == 0) { redA[wv] = es; redB[wv] = ef; }  // wv in [8,16)
    }
    __syncthreads();  // B2

    // ---- P3: LSTM pointwise (tid < 512) ----
    if (tid < 512) {
      const int rb = 8 + gp * 4;
      float es = redA[rb + 0] + redA[rb + 1] + redA[rb + 2] + redA[rb + 3];
      float ef = redB[rb + 0] + redB[rb + 1] + redB[rb + 2] + redB[rb + 3];
      float yt = ef * rcpf_(es) + fmaf(yhL[gp][s], fcwy, fcb0);
      float gi = fmaf(yt, Wihl[lo], bl[lo]);
      float gf = fmaf(yt, Wihl[256 + lo], bl[256 + lo]);
      float gc = fmaf(yt, Wihl[512 + lo], bl[512 + lo]);
      float go = fmaf(yt, Wihl[768 + lo], bl[768 + lo]);
      gi += gpart[0][gp][lo] + gpart[1][gp][lo];
      gf += gpart[0][gp][256 + lo] + gpart[1][gp][256 + lo];
      gc += gpart[0][gp][512 + lo] + gpart[1][gp][512 + lo];
      go += gpart[0][gp][768 + lo] + gpart[1][gp][768 + lo];
      float iv = sigmoidf_(gi), fv = sigmoidf_(gf), gv = tanhf_(gc), ov = sigmoidf_(go);
      float cold = hc[gp][256 + lo];
      float cn = fmaf(fv, cold, iv * gv);
      float hn = ov * tanhf_(cn);
      hc[gp][lo] = hn;
      hc[gp][256 + lo] = cn;
      hcH[gp][lo] = (_Float16)hn;
      hcH[gp][256 + lo] = (_Float16)cn;
    }
    __syncthreads();  // B3
  }

  // ---- epilogue: context from step-255 ealpha, then out = [h|ctx].fcf ----
  // last-step softmax sums live in redA[8..15]; epilogue reuses redA[0..7] only
  const float rsA = rcpf_(redA[8] + redA[9] + redA[10] + redA[11]);
  const float rsB = rcpf_(redA[12] + redA[13] + redA[14] + redA[15]);

  float* cpartF = &gpart[0][0][0];  // alias: cpart[g][u][t] = cpartF[(g*16+u)*256+t] (32KB)
  {
    const int gc = tid >> 9, t16 = (tid >> 5) & 15, l5 = tid & 31;
    const half8* xrow = reinterpret_cast<const half8*>(xh) +
                        ((size_t)(b0 + gc) * 256 + t16 * 16) * 32 + l5;
    float acx[8];
#pragma unroll
    for (int m = 0; m < 8; ++m) acx[m] = 0.f;
#pragma unroll 4
    for (int it = 0; it < 16; ++it) {
      float al = ealpha[gc][t16 * 16 + it];
      half8 xv = xrow[it * 32];
#pragma unroll
      for (int m = 0; m < 8; ++m) acx[m] = fmaf(al, (float)xv[m], acx[m]);
    }
    float* dst = &cpartF[((gc * 16 + t16) * 256) + l5 * 8];
    *reinterpret_cast<float4*>(dst) = *reinterpret_cast<float4*>(&acx[0]);
    *reinterpret_cast<float4*>(dst + 4) = *reinterpret_cast<float4*>(&acx[4]);
  }
  __syncthreads();

  if (tid < 512) {
    float cv = 0.f;
#pragma unroll
    for (int u = 0; u < 16; ++u) cv += cpartF[((gp * 16 + u) * 256) + lo];
    cv *= (gp == 0) ? rsA : rsB;
    float hval = hc[gp][lo];
    float p0 = hval * fcfw[lo] + cv * fcfw[256 + lo];
    float p1 = hval * fcfw[512 + lo] + cv * fcfw[768 + lo];
#pragma unroll
    for (int off = 32; off > 0; off >>= 1) {
      p0 += __shfl_xor(p0, off);
      p1 += __shfl_xor(p1, off);
    }
    if (lane == 0) { redA[wv] = p0; redB[wv] = p1; }  // wv in [0,8)
  }
  __syncthreads();
  if (tid < 4) {
    int g2 = tid >> 1, o = tid & 1;
    const float* r = (o == 0) ? redA : redB;
    float v = fcfb[o] + r[g2 * 4 + 0] + r[g2 * 4 + 1] + r[g2 * 4 + 2] + r[g2 * 4 + 3];
    out[(b0 + g2) * 2 + o] = v;
  }
}

extern "C" void kernel_launch(void* const* d_in, const int* in_sizes, int n_in,
                              void* d_out, int out_size, void* d_ws, size_t ws_size,
                              hipStream_t stream) {
  (void)in_sizes; (void)n_in; (void)out_size; (void)ws_size;
  const float* x    = (const float*)d_in[0];
  const float* yh   = (const float*)d_in[1];
  const float* w1   = (const float*)d_in[2];
  const float* b1   = (const float*)d_in[3];
  const float* w2   = (const float*)d_in[4];
  /* d_in[5] attn_b2: softmax-invariant, unused */
  const float* Wih  = (const float*)d_in[6];
  const float* Whh  = (const float*)d_in[7];
  const float* bih  = (const float*)d_in[8];
  const float* bhh  = (const float*)d_in[9];
  const float* fcw  = (const float*)d_in[10];
  const float* fcb  = (const float*)d_in[11];
  const float* fcfw = (const float*)d_in[12];
  const float* fcfb = (const float*)d_in[13];
  float* out = (float*)d_out;

  char* ws = (char*)d_ws;
  _Float16* Ph2   = (_Float16*)(ws);                      // 67108864 B
  _Float16* xh    = (_Float16*)(ws + (size_t)67108864);   // 67108864 B
  float*    wT    = (float*)   (ws + (size_t)134217728);  // 262144 B
  _Float16* w1hcQ = (_Float16*)(ws + (size_t)134479872);  // 262144 B
  _Float16* whhG  = (_Float16*)(ws + (size_t)134742016);  // 524288 B
  float*    xf    = (float*)   (ws + (size_t)135266304);  // 524288 B
  // total: 135790592 B (~129.5 MB)

  k_prep_wT   <<<256,   256, 0, stream>>>(w1, wT);
  k_prep_xh   <<<32768, 256, 0, stream>>>(x, xh);
  k_prep_w1hcQ<<<512,   256, 0, stream>>>(w1, w1hcQ);
  k_prep_whhG <<<1024,  256, 0, stream>>>(Whh, whhG);
  k_xf        <<<8192,  256, 0, stream>>>(x, fcw, xf);
  k_encp      <<<8192,  256, 0, stream>>>(x, wT, b1, Ph2);
  k_scan      <<<256,  1024, 0, stream>>>(Ph2, xh, w1hcQ, whhG, xf, yh, w2, Wih,
                                          bih, bhh, fcw, fcb, fcfw, fcfb, out);
}

// Round 10
// 4743.092 us; speedup vs baseline: 2.0019x; 1.3593x over previous
//
#include <hip/hip_runtime.h>
#include <cstdint>
#include <cstddef>

// Decoder (DA-RNN): B=512, T=256, E=D=256.
// Round 12: exact R6/R8-base kernel (verified best, 5040us k_scan) with ONE
// token changed: Ph2 loads in phase 3 are PLAIN loads (nontemporal hint
// removed). Hypothesis: nt/slc bits were marking Ph2 lines evict-first
// through the MALL, defeating L3 retention of a 64MB buffer that fits 4x in
// the 256MB Infinity Cache (evidence: 16GB of Ph2 re-reads but FETCH_SIZE
// 5.8GB => ~36% served from HBM). Primary readout: FETCH_SIZE <2e6 KB.
// Everything else byte-identical to R6: 256 blocks x 1024 threads, G=2,
// wave-uniform k-splits (conflict-free), 5 barriers/step.

typedef _Float16 half8 __attribute__((ext_vector_type(8)));
typedef _Float16 half4v __attribute__((ext_vector_type(4)));
typedef _Float16 half2v __attribute__((ext_vector_type(2)));

__device__ __forceinline__ float rcpf_(float x) { return __builtin_amdgcn_rcpf(x); }
__device__ __forceinline__ float sigmoidf_(float x) { return rcpf_(1.f + __expf(-x)); }
__device__ __forceinline__ float tanhf_(float x) { return 1.f - 2.f * rcpf_(1.f + __expf(2.f * x)); }

#if defined(__has_builtin)
#if __has_builtin(__builtin_amdgcn_fdot2)
#define HAS_FDOT2 1
#endif
#endif
#ifndef HAS_FDOT2
#define HAS_FDOT2 0
#endif

__device__ __forceinline__ float fdot2_(half2v a, half2v b, float c) {
#if HAS_FDOT2
  return __builtin_amdgcn_fdot2(a, b, c, false);
#else
  return fmaf((float)a[0], (float)b[0], fmaf((float)a[1], (float)b[1], c));
#endif
}

__device__ __forceinline__ float dot8_(half8 w, half8 h, float acc) {
  acc = fdot2_(__builtin_shufflevector(w, w, 0, 1), __builtin_shufflevector(h, h, 0, 1), acc);
  acc = fdot2_(__builtin_shufflevector(w, w, 2, 3), __builtin_shufflevector(h, h, 2, 3), acc);
  acc = fdot2_(__builtin_shufflevector(w, w, 4, 5), __builtin_shufflevector(h, h, 4, 5), acc);
  acc = fdot2_(__builtin_shufflevector(w, w, 6, 7), __builtin_shufflevector(h, h, 6, 7), acc);
  return acc;
}

// ---------------- prep kernels ----------------

// wT[e*256+f] = attn_w1[f*768 + 512 + e]   (transposed w1_enc, fp32)
__global__ void k_prep_wT(const float* __restrict__ w1, float* __restrict__ wT) {
  int id = blockIdx.x * 256 + threadIdx.x;
  int e = id >> 8, f = id & 255;
  wT[id] = w1[f * 768 + 512 + e];
}

// x -> fp16 (4 elems/thread), layout unchanged [b][t][e]
__global__ void k_prep_xh(const float* __restrict__ x, _Float16* __restrict__ xh) {
  int id = blockIdx.x * 256 + threadIdx.x;
  float4 v = reinterpret_cast<const float4*>(x)[id];
  half4v h;
  h[0] = (_Float16)v.x; h[1] = (_Float16)v.y; h[2] = (_Float16)v.z; h[3] = (_Float16)v.w;
  reinterpret_cast<half4v*>(xh)[id] = h;
}

// w1hcQ[(c*1024 + t)*8 + m] = w1[e*768 + k],  t = jk*256 + e  (jk = t>>8
// wave-uniform in k_scan), k = jk*128 + c*8 + m, c in [0,16)
__global__ void k_prep_w1hcQ(const float* __restrict__ w1, _Float16* __restrict__ o) {
  int id = blockIdx.x * 256 + threadIdx.x;  // 131072 total
  int m = id & 7, t = (id >> 3) & 1023, c = id >> 13;
  int e = t & 255, jk = t >> 8;
  int k = jk * 128 + c * 8 + m;
  o[id] = (_Float16)w1[e * 768 + k];
}

// whhG[(((jk*8 + c)*4 + jslot)*256 + jo)*8 + m] = Whh[(jslot*256+jo)*256 + jk*64 + c*8 + m]
// (thread (jo, jk=tid>>8) computes 4 outputs jslot*256+jo over k in [jk*64,+64))
__global__ void k_prep_whhG(const float* __restrict__ whh, _Float16* __restrict__ o) {
  int id = blockIdx.x * 256 + threadIdx.x;  // 262144 total
  int m = id & 7, jo = (id >> 3) & 255, jslot = (id >> 11) & 3;
  int c = (id >> 13) & 7, jk = id >> 16;
  int j = jslot * 256 + jo, k = jk * 64 + c * 8 + m;
  o[id] = (_Float16)whh[j * 256 + k];
}

// xf[b*256+t] = sum_e x[b,t,e] * fcw[e]   (fp32)
__global__ __launch_bounds__(256) void k_xf(const float* __restrict__ x,
                                            const float* __restrict__ fcw,
                                            float* __restrict__ xf) {
  __shared__ float xl[16][256];
  __shared__ float fw[256];
  __shared__ float part[16][17];
  const int tid = threadIdx.x;
  const int m0 = blockIdx.x * 16;
  fw[tid] = fcw[tid];
#pragma unroll
  for (int r = 0; r < 16; ++r) xl[r][tid] = x[(size_t)(m0 + r) * 256 + tid];
  __syncthreads();
  int r = tid >> 4, p = tid & 15;
  float s = 0.f;
#pragma unroll
  for (int u = 0; u < 16; ++u) s = fmaf(xl[r][p * 16 + u], fw[p * 16 + u], s);
  part[r][p] = s;
  __syncthreads();
  if (tid < 16) {
    float t = 0.f;
#pragma unroll
    for (int p2 = 0; p2 < 16; ++p2) t += part[tid][p2];
    xf[m0 + tid] = t;
  }
}

// enc_proj GEMM + bias, store P=exp(2*encp) fp16 in layout [b][e/8][t][e%8]
__global__ __launch_bounds__(256) void k_encp(const float* __restrict__ x,
                                              const float* __restrict__ wT,
                                              const float* __restrict__ b1,
                                              _Float16* __restrict__ Ph2) {
  __shared__ __align__(16) float xl[16][256];
  const int tid = threadIdx.x;
  const int m0 = blockIdx.x * 16;
#pragma unroll
  for (int r = 0; r < 16; ++r) xl[r][tid] = x[(size_t)(m0 + r) * 256 + tid];
  __syncthreads();
  float acc[16];
#pragma unroll
  for (int r = 0; r < 16; ++r) acc[r] = 0.f;
  for (int e = 0; e < 256; e += 4) {
    float w0 = wT[(e + 0) * 256 + tid];
    float w1_ = wT[(e + 1) * 256 + tid];
    float w2_ = wT[(e + 2) * 256 + tid];
    float w3_ = wT[(e + 3) * 256 + tid];
#pragma unroll
    for (int r = 0; r < 16; ++r) {
      float4 xv = *reinterpret_cast<const float4*>(&xl[r][e]);
      acc[r] = fmaf(xv.x, w0, acc[r]);
      acc[r] = fmaf(xv.y, w1_, acc[r]);
      acc[r] = fmaf(xv.z, w2_, acc[r]);
      acc[r] = fmaf(xv.w, w3_, acc[r]);
    }
  }
  float bb = b1[tid];
  const int e = tid;
#pragma unroll
  for (int r = 0; r < 16; ++r) {
    int m = m0 + r, b = m >> 8, t = m & 255;
    float p = __expf(2.f * (acc[r] + bb));
    Ph2[((size_t)(b * 32 + (e >> 3)) * 256 + t) * 8 + (e & 7)] = (_Float16)p;
  }
}

// ---------------- the scan ----------------
// grid 256 x 1024 threads; wg owns 2 batch rows; 256 steps; 16 waves/CU.
__global__ __launch_bounds__(1024, 4) void k_scan(
    const _Float16* __restrict__ Ph2, const _Float16* __restrict__ xh,
    const _Float16* __restrict__ w1hcQ, const _Float16* __restrict__ whhG,
    const float* __restrict__ xf, const float* __restrict__ y_hist,
    const float* __restrict__ w2g, const float* __restrict__ Wih,
    const float* __restrict__ bih, const float* __restrict__ bhh,
    const float* __restrict__ fcw, const float* __restrict__ fcb,
    const float* __restrict__ fcfw, const float* __restrict__ fcfb,
    float* __restrict__ out) {
  __shared__ __align__(16) float hc[2][512];        // fp32 [g][ h | c ]
  __shared__ __align__(16) _Float16 hcH[2][512];    // fp16 mirror for dot2
  __shared__ __align__(16) float qpart[4][2][256];  // [jk][g][e]
  __shared__ __align__(16) float Qs[2][256];        // exp(2q)
  __shared__ __align__(16) float spart[2][2][256];  // [eh][g][t]
  __shared__ __align__(16) float ealpha[2][256];
  __shared__ __align__(16) float gpart[4][2][1024]; // [jk][g][j]; aliased post-loop as cpart[2][16][256]
  __shared__ __align__(16) float w2l[256];
  __shared__ __align__(16) float Wihl[1024];
  __shared__ __align__(16) float bl[1024];
  __shared__ __align__(16) float xfL[2][256];
  __shared__ __align__(16) float yhL[2][256];
  __shared__ float redA[8], redB[8];

  const int tid = threadIdx.x;
  const int b0 = blockIdx.x * 2;
  const int hi = tid >> 8;     // 0..3, wave-uniform
  const int lo = tid & 255;
  const int wv = tid >> 6, lane = tid & 63;

  // ---- init ----
  ((float*)hc)[tid] = 0.f;
  ((_Float16*)hcH)[tid] = (_Float16)0.f;
  if (tid < 256) w2l[tid] = w2g[tid];
  Wihl[tid & 1023] = Wih[tid & 1023];
  bl[tid] = bih[tid] + bhh[tid];
  if (tid < 512) {
    int gi = tid >> 8, ti = tid & 255;
    xfL[gi][ti] = xf[(size_t)(b0 + gi) * 256 + ti];
    yhL[gi][ti] = y_hist[(size_t)(b0 + gi) * 256 + ti];
  }
  __syncthreads();
  float w2sum = 0.f;
  for (int e2 = 0; e2 < 256; ++e2) w2sum += w2l[e2];
  const float fcb0 = fcb[0];
  const float fcwy = fcw[256];

  // per-thread role constants
  // q phase: thread = (jk = hi, e = lo), k in [jk*128, +128)  [wave-uniform jk]
  const half8* wq = reinterpret_cast<const half8*>(w1hcQ) + tid;  // chunk c: wq[c*1024]
  // gates: thread = (jo = lo, jk = hi); outputs jslot*256+jo, k in [jk*64, +64)
  const half8* wg = reinterpret_cast<const half8*>(whhG) + (size_t)hi * 8192 + lo;
  // scores: thread = (g = tid>>9, eh = (tid>>8)&1, t = lo), e in [eh*128, +128)
  const int gs = tid >> 9, eh = (tid >> 8) & 1;
  const half8* prow = reinterpret_cast<const half8*>(Ph2) +
                      ((size_t)((b0 + gs) * 32 + eh * 16)) * 256 + lo;
  // pointwise / softmax-combine (tid < 512)
  const int gp = (tid >> 8) & 1;

#pragma unroll 1
  for (int s = 0; s < 256; ++s) {
    // ---- phase 1: q[e] = hc . w1_hc[e,:], k-split 4 (wave-uniform), both rows ----
    float a0 = 0.f, a1 = 0.f;
    {
      const half8* hp0 = reinterpret_cast<const half8*>(&hcH[0][hi * 128]);
      const half8* hp1 = reinterpret_cast<const half8*>(&hcH[1][hi * 128]);
#pragma unroll 8
      for (int c = 0; c < 16; ++c) {
        half8 w = wq[c * 1024];
        half8 h0 = hp0[c];   // broadcast read (same addr across wave)
        half8 h1 = hp1[c];
        a0 = dot8_(w, h0, a0);
        a1 = dot8_(w, h1, a1);
      }
    }
    qpart[hi][0][lo] = a0;
    qpart[hi][1][lo] = a1;
    __syncthreads();  // B1

    // ---- phase 2: Qs (tid<512) + gates GEMV h@Whh (all threads, both rows) ----
    if (tid < 512) {
      float qv = qpart[0][gp][lo] + qpart[1][gp][lo] + qpart[2][gp][lo] + qpart[3][gp][lo];
      Qs[gp][lo] = __expf(2.f * qv);
    }
    float ac0[4], ac1[4];
#pragma unroll
    for (int m = 0; m < 4; ++m) { ac0[m] = 0.f; ac1[m] = 0.f; }
    {
      const half8* hg0 = reinterpret_cast<const half8*>(&hcH[0][hi * 64]);
      const half8* hg1 = reinterpret_cast<const half8*>(&hcH[1][hi * 64]);
#pragma unroll 2
      for (int c = 0; c < 8; ++c) {
        half8 h0 = hg0[c];   // broadcast
        half8 h1 = hg1[c];
#pragma unroll
        for (int jslot = 0; jslot < 4; ++jslot) {
          half8 w = wg[(c * 4 + jslot) * 256];
          ac0[jslot] = dot8_(w, h0, ac0[jslot]);
          ac1[jslot] = dot8_(w, h1, ac1[jslot]);
        }
      }
    }
#pragma unroll
    for (int jslot = 0; jslot < 4; ++jslot) {
      gpart[hi][0][jslot * 256 + lo] = ac0[jslot];
      gpart[hi][1][jslot * 256 + lo] = ac1[jslot];
    }
    __syncthreads();  // B2

    // ---- phase 3: scores, e-split 2: sacc = sum_e w2[e]/(P*Q+1) ----
    // PLAIN loads (the single change vs R6): let Ph2 retain in L2/L3.
    float sacc0 = 0.f, sacc1 = 0.f;
    {
      const float4* q4 = reinterpret_cast<const float4*>(&Qs[gs][eh * 128]);
      const float4* w4 = reinterpret_cast<const float4*>(&w2l[eh * 128]);
#pragma unroll 8
      for (int c = 0; c < 16; ++c) {
        half8 pv = prow[c * 256];
        float4 qa = q4[2 * c], qb = q4[2 * c + 1];
        float4 wa = w4[2 * c], wb = w4[2 * c + 1];
        sacc0 = fmaf(wa.x, rcpf_(fmaf((float)pv[0], qa.x, 1.f)), sacc0);
        sacc1 = fmaf(wa.y, rcpf_(fmaf((float)pv[1], qa.y, 1.f)), sacc1);
        sacc0 = fmaf(wa.z, rcpf_(fmaf((float)pv[2], qa.z, 1.f)), sacc0);
        sacc1 = fmaf(wa.w, rcpf_(fmaf((float)pv[3], qa.w, 1.f)), sacc1);
        sacc0 = fmaf(wb.x, rcpf_(fmaf((float)pv[4], qb.x, 1.f)), sacc0);
        sacc1 = fmaf(wb.y, rcpf_(fmaf((float)pv[5], qb.y, 1.f)), sacc1);
        sacc0 = fmaf(wb.z, rcpf_(fmaf((float)pv[6], qb.z, 1.f)), sacc0);
        sacc1 = fmaf(wb.w, rcpf_(fmaf((float)pv[7], qb.w, 1.f)), sacc1);
      }
    }
    spart[eh][gs][lo] = sacc0 + sacc1;
    __syncthreads();  // B3

    // ---- phase 4: combine + softmax reduce (tid < 512) ----
    if (tid < 512) {
      float sc = w2sum - 2.f * (spart[0][gp][lo] + spart[1][gp][lo]);
      float ea = __expf(sc);  // no max-sub: |sc| <= ~21, fp32-safe
      ealpha[gp][lo] = ea;
      float ef = ea * xfL[gp][lo];
      float es = ea;
#pragma unroll
      for (int off = 32; off > 0; off >>= 1) {
        es += __shfl_xor(es, off);
        ef += __shfl_xor(ef, off);
      }
      if (lane == 0) { redA[wv] = es; redB[wv] = ef; }
    }
    __syncthreads();  // B4

    // ---- phase 5: LSTM pointwise (tid < 512) ----
    if (tid < 512) {
      float es = (gp == 0) ? (redA[0] + redA[1] + redA[2] + redA[3])
                           : (redA[4] + redA[5] + redA[6] + redA[7]);
      float ef = (gp == 0) ? (redB[0] + redB[1] + redB[2] + redB[3])
                           : (redB[4] + redB[5] + redB[6] + redB[7]);
      float yt = ef * rcpf_(es) + fmaf(yhL[gp][s], fcwy, fcb0);
      float gi = fmaf(yt, Wihl[lo], bl[lo]);
      float gf = fmaf(yt, Wihl[256 + lo], bl[256 + lo]);
      float gc = fmaf(yt, Wihl[512 + lo], bl[512 + lo]);
      float go = fmaf(yt, Wihl[768 + lo], bl[768 + lo]);
#pragma unroll
      for (int q2 = 0; q2 < 4; ++q2) {
        gi += gpart[q2][gp][lo];
        gf += gpart[q2][gp][256 + lo];
        gc += gpart[q2][gp][512 + lo];
        go += gpart[q2][gp][768 + lo];
      }
      float iv = sigmoidf_(gi), fv = sigmoidf_(gf), gv = tanhf_(gc), ov = sigmoidf_(go);
      float cold = hc[gp][256 + lo];
      float cn = fmaf(fv, cold, iv * gv);
      float hn = ov * tanhf_(cn);
      hc[gp][lo] = hn;
      hc[gp][256 + lo] = cn;
      hcH[gp][lo] = (_Float16)hn;
      hcH[gp][256 + lo] = (_Float16)cn;
    }
    __syncthreads();  // B5
  }

  // ---- epilogue: context from step-255 ealpha, then out = [h|ctx].fcf ----
  // read last-step softmax sums BEFORE redA/redB get reused
  const float rsA = rcpf_(redA[0] + redA[1] + redA[2] + redA[3]);
  const float rsB = rcpf_(redA[4] + redA[5] + redA[6] + redA[7]);

  float* cpartF = &gpart[0][0][0];  // alias: cpart[g][u][t] = cpartF[(g*16+u)*256+t]
  {
    const int gc = tid >> 9, t16 = (tid >> 5) & 15, l5 = tid & 31;
    const half8* xrow = reinterpret_cast<const half8*>(xh) +
                        ((size_t)(b0 + gc) * 256 + t16 * 16) * 32 + l5;
    float acx[8];
#pragma unroll
    for (int m = 0; m < 8; ++m) acx[m] = 0.f;
#pragma unroll 4
    for (int it = 0; it < 16; ++it) {
      float al = ealpha[gc][t16 * 16 + it];
      half8 xv = xrow[it * 32];
#pragma unroll
      for (int m = 0; m < 8; ++m) acx[m] = fmaf(al, (float)xv[m], acx[m]);
    }
    float* dst = &cpartF[((gc * 16 + t16) * 256) + l5 * 8];
    *reinterpret_cast<float4*>(dst) = *reinterpret_cast<float4*>(&acx[0]);
    *reinterpret_cast<float4*>(dst + 4) = *reinterpret_cast<float4*>(&acx[4]);
  }
  __syncthreads();

  if (tid < 512) {
    float cv = 0.f;
#pragma unroll
    for (int u = 0; u < 16; ++u) cv += cpartF[((gp * 16 + u) * 256) + lo];
    cv *= (gp == 0) ? rsA : rsB;
    float hval = hc[gp][lo];
    float p0 = hval * fcfw[lo] + cv * fcfw[256 + lo];
    float p1 = hval * fcfw[512 + lo] + cv * fcfw[768 + lo];
#pragma unroll
    for (int off = 32; off > 0; off >>= 1) {
      p0 += __shfl_xor(p0, off);
      p1 += __shfl_xor(p1, off);
    }
    if (lane == 0) { redA[wv] = p0; redB[wv] = p1; }
  }
  __syncthreads();
  if (tid < 4) {
    int g2 = tid >> 1, o = tid & 1;
    const float* r = (o == 0) ? redA : redB;
    float v = fcfb[o] + r[g2 * 4 + 0] + r[g2 * 4 + 1] + r[g2 * 4 + 2] + r[g2 * 4 + 3];
    out[(b0 + g2) * 2 + o] = v;
  }
}

extern "C" void kernel_launch(void* const* d_in, const int* in_sizes, int n_in,
                              void* d_out, int out_size, void* d_ws, size_t ws_size,
                              hipStream_t stream) {
  (void)in_sizes; (void)n_in; (void)out_size; (void)ws_size;
  const float* x    = (const float*)d_in[0];
  const float* yh   = (const float*)d_in[1];
  const float* w1   = (const float*)d_in[2];
  const float* b1   = (const float*)d_in[3];
  const float* w2   = (const float*)d_in[4];
  /* d_in[5] attn_b2: softmax-invariant, unused */
  const float* Wih  = (const float*)d_in[6];
  const float* Whh  = (const float*)d_in[7];
  const float* bih  = (const float*)d_in[8];
  const float* bhh  = (const float*)d_in[9];
  const float* fcw  = (const float*)d_in[10];
  const float* fcb  = (const float*)d_in[11];
  const float* fcfw = (const float*)d_in[12];
  const float* fcfb = (const float*)d_in[13];
  float* out = (float*)d_out;

  char* ws = (char*)d_ws;
  _Float16* Ph2   = (_Float16*)(ws);                      // 67108864 B
  _Float16* xh    = (_Float16*)(ws + (size_t)67108864);   // 67108864 B
  float*    wT    = (float*)   (ws + (size_t)134217728);  // 262144 B
  _Float16* w1hcQ = (_Float16*)(ws + (size_t)134479872);  // 262144 B
  _Float16* whhG  = (_Float16*)(ws + (size_t)134742016);  // 524288 B
  float*    xf    = (float*)   (ws + (size_t)135266304);  // 524288 B
  // total: 135790592 B (~129.5 MB)

  k_prep_wT   <<<256,   256, 0, stream>>>(w1, wT);
  k_prep_xh   <<<32768, 256, 0, stream>>>(x, xh);
  k_prep_w1hcQ<<<512,   256, 0, stream>>>(w1, w1hcQ);
  k_prep_whhG <<<1024,  256, 0, stream>>>(Whh, whhG);
  k_xf        <<<8192,  256, 0, stream>>>(x, fcw, xf);
  k_encp      <<<8192,  256, 0, stream>>>(x, wT, b1, Ph2);
  k_scan      <<<256,  1024, 0, stream>>>(Ph2, xh, w1hcQ, whhG, xf, yh, w2, Wih,
                                          bih, bhh, fcw, fcb, fcfw, fcfb, out);
}

// Round 11
// 4078.123 us; speedup vs baseline: 2.3283x; 1.1631x over previous
//
#include <hip/hip_runtime.h>
#include <cstdint>
#include <cstddef>

// Decoder (DA-RNN): B=512, T=256, E=D=256.
// Round 13: base = R12 (best, 4550us k_scan, plain Ph2 loads). Key fact newly
// exploited: each block re-reads the SAME 256KB Ph2 slice every one of the
// 256 steps (step-invariant addresses) -> 16GB repeat traffic. Change:
//  (A) stage 12/32 chunks per row (96KB, balanced 6 per eh-half) in LDS ONCE
//      in the prologue; phase 3 reads 6 chunks from LDS + 10 from global
//      (-37.5% streamed bytes, less L2 pollution of the weight streams).
//  (B) to fit: gates k-split 4->2 (gpart 32->16KB, same 64 dot8/thread,
//      R9-proven whhG layout). Working LDS 51KB + 96KB stage = 147KB <= 160.
// No register state crosses any barrier (5x-confirmed allocator constraint).

typedef _Float16 half8 __attribute__((ext_vector_type(8)));
typedef _Float16 half4v __attribute__((ext_vector_type(4)));
typedef _Float16 half2v __attribute__((ext_vector_type(2)));

__device__ __forceinline__ float rcpf_(float x) { return __builtin_amdgcn_rcpf(x); }
__device__ __forceinline__ float sigmoidf_(float x) { return rcpf_(1.f + __expf(-x)); }
__device__ __forceinline__ float tanhf_(float x) { return 1.f - 2.f * rcpf_(1.f + __expf(2.f * x)); }

#if defined(__has_builtin)
#if __has_builtin(__builtin_amdgcn_fdot2)
#define HAS_FDOT2 1
#endif
#endif
#ifndef HAS_FDOT2
#define HAS_FDOT2 0
#endif

__device__ __forceinline__ float fdot2_(half2v a, half2v b, float c) {
#if HAS_FDOT2
  return __builtin_amdgcn_fdot2(a, b, c, false);
#else
  return fmaf((float)a[0], (float)b[0], fmaf((float)a[1], (float)b[1], c));
#endif
}

__device__ __forceinline__ float dot8_(half8 w, half8 h, float acc) {
  acc = fdot2_(__builtin_shufflevector(w, w, 0, 1), __builtin_shufflevector(h, h, 0, 1), acc);
  acc = fdot2_(__builtin_shufflevector(w, w, 2, 3), __builtin_shufflevector(h, h, 2, 3), acc);
  acc = fdot2_(__builtin_shufflevector(w, w, 4, 5), __builtin_shufflevector(h, h, 4, 5), acc);
  acc = fdot2_(__builtin_shufflevector(w, w, 6, 7), __builtin_shufflevector(h, h, 6, 7), acc);
  return acc;
}

// ---------------- prep kernels ----------------

// wT[e*256+f] = attn_w1[f*768 + 512 + e]   (transposed w1_enc, fp32)
__global__ void k_prep_wT(const float* __restrict__ w1, float* __restrict__ wT) {
  int id = blockIdx.x * 256 + threadIdx.x;
  int e = id >> 8, f = id & 255;
  wT[id] = w1[f * 768 + 512 + e];
}

// x -> fp16 (4 elems/thread), layout unchanged [b][t][e]
__global__ void k_prep_xh(const float* __restrict__ x, _Float16* __restrict__ xh) {
  int id = blockIdx.x * 256 + threadIdx.x;
  float4 v = reinterpret_cast<const float4*>(x)[id];
  half4v h;
  h[0] = (_Float16)v.x; h[1] = (_Float16)v.y; h[2] = (_Float16)v.z; h[3] = (_Float16)v.w;
  reinterpret_cast<half4v*>(xh)[id] = h;
}

// w1hcQ[(c*1024 + t)*8 + m] = w1[e*768 + k],  t = jk*256 + e  (jk = t>>8
// wave-uniform in k_scan), k = jk*128 + c*8 + m, c in [0,16)
__global__ void k_prep_w1hcQ(const float* __restrict__ w1, _Float16* __restrict__ o) {
  int id = blockIdx.x * 256 + threadIdx.x;  // 131072 total
  int m = id & 7, t = (id >> 3) & 1023, c = id >> 13;
  int e = t & 255, jk = t >> 8;
  int k = jk * 128 + c * 8 + m;
  o[id] = (_Float16)w1[e * 768 + k];
}

// whhG[(((kh*16 + c)*4 + js)*256 + jo)*8 + m] = Whh[(js*256+jo)*256 + kh*128 + c*8 + m]
// (thread (jo, kh=hi&1, jp=hi>>1) computes outputs {jp*2,jp*2+1}*256+jo over
// k in [kh*128,+128))
__global__ void k_prep_whhG(const float* __restrict__ whh, _Float16* __restrict__ o) {
  int id = blockIdx.x * 256 + threadIdx.x;  // 262144 total
  int m = id & 7, jo = (id >> 3) & 255, js = (id >> 11) & 3;
  int c = (id >> 13) & 15, kh = id >> 17;
  int j = js * 256 + jo, k = kh * 128 + c * 8 + m;
  o[id] = (_Float16)whh[j * 256 + k];
}

// xf[b*256+t] = sum_e x[b,t,e] * fcw[e]   (fp32)
__global__ __launch_bounds__(256) void k_xf(const float* __restrict__ x,
                                            const float* __restrict__ fcw,
                                            float* __restrict__ xf) {
  __shared__ float xl[16][256];
  __shared__ float fw[256];
  __shared__ float part[16][17];
  const int tid = threadIdx.x;
  const int m0 = blockIdx.x * 16;
  fw[tid] = fcw[tid];
#pragma unroll
  for (int r = 0; r < 16; ++r) xl[r][tid] = x[(size_t)(m0 + r) * 256 + tid];
  __syncthreads();
  int r = tid >> 4, p = tid & 15;
  float s = 0.f;
#pragma unroll
  for (int u = 0; u < 16; ++u) s = fmaf(xl[r][p * 16 + u], fw[p * 16 + u], s);
  part[r][p] = s;
  __syncthreads();
  if (tid < 16) {
    float t = 0.f;
#pragma unroll
    for (int p2 = 0; p2 < 16; ++p2) t += part[tid][p2];
    xf[m0 + tid] = t;
  }
}

// enc_proj GEMM + bias, store P=exp(2*encp) fp16 in layout [b][e/8][t][e%8]
__global__ __launch_bounds__(256) void k_encp(const float* __restrict__ x,
                                              const float* __restrict__ wT,
                                              const float* __restrict__ b1,
                                              _Float16* __restrict__ Ph2) {
  __shared__ __align__(16) float xl[16][256];
  const int tid = threadIdx.x;
  const int m0 = blockIdx.x * 16;
#pragma unroll
  for (int r = 0; r < 16; ++r) xl[r][tid] = x[(size_t)(m0 + r) * 256 + tid];
  __syncthreads();
  float acc[16];
#pragma unroll
  for (int r = 0; r < 16; ++r) acc[r] = 0.f;
  for (int e = 0; e < 256; e += 4) {
    float w0 = wT[(e + 0) * 256 + tid];
    float w1_ = wT[(e + 1) * 256 + tid];
    float w2_ = wT[(e + 2) * 256 + tid];
    float w3_ = wT[(e + 3) * 256 + tid];
#pragma unroll
    for (int r = 0; r < 16; ++r) {
      float4 xv = *reinterpret_cast<const float4*>(&xl[r][e]);
      acc[r] = fmaf(xv.x, w0, acc[r]);
      acc[r] = fmaf(xv.y, w1_, acc[r]);
      acc[r] = fmaf(xv.z, w2_, acc[r]);
      acc[r] = fmaf(xv.w, w3_, acc[r]);
    }
  }
  float bb = b1[tid];
  const int e = tid;
#pragma unroll
  for (int r = 0; r < 16; ++r) {
    int m = m0 + r, b = m >> 8, t = m & 255;
    float p = __expf(2.f * (acc[r] + bb));
    Ph2[((size_t)(b * 32 + (e >> 3)) * 256 + t) * 8 + (e & 7)] = (_Float16)p;
  }
}

#define SC1(pv, c) { \
  float4 qa = q4[2*(c)], wa = w4[2*(c)]; \
  sacc0 = fmaf(wa.x, rcpf_(fmaf((float)pv[0], qa.x, 1.f)), sacc0); \
  sacc1 = fmaf(wa.y, rcpf_(fmaf((float)pv[1], qa.y, 1.f)), sacc1); \
  sacc0 = fmaf(wa.z, rcpf_(fmaf((float)pv[2], qa.z, 1.f)), sacc0); \
  sacc1 = fmaf(wa.w, rcpf_(fmaf((float)pv[3], qa.w, 1.f)), sacc1); \
  float4 qb = q4[2*(c)+1], wb = w4[2*(c)+1]; \
  sacc0 = fmaf(wb.x, rcpf_(fmaf((float)pv[4], qb.x, 1.f)), sacc0); \
  sacc1 = fmaf(wb.y, rcpf_(fmaf((float)pv[5], qb.y, 1.f)), sacc1); \
  sacc0 = fmaf(wb.z, rcpf_(fmaf((float)pv[6], qb.z, 1.f)), sacc0); \
  sacc1 = fmaf(wb.w, rcpf_(fmaf((float)pv[7], qb.w, 1.f)), sacc1); }

// ---------------- the scan ----------------
// grid 256 x 1024 threads; wg owns 2 batch rows; 256 steps; 16 waves/CU.
__global__ __launch_bounds__(1024, 4) void k_scan(
    const _Float16* __restrict__ Ph2, const _Float16* __restrict__ xh,
    const _Float16* __restrict__ w1hcQ, const _Float16* __restrict__ whhG,
    const float* __restrict__ xf, const float* __restrict__ y_hist,
    const float* __restrict__ w2g, const float* __restrict__ Wih,
    const float* __restrict__ bih, const float* __restrict__ bhh,
    const float* __restrict__ fcw, const float* __restrict__ fcb,
    const float* __restrict__ fcfw, const float* __restrict__ fcfb,
    float* __restrict__ out) {
  __shared__ __align__(16) float hc[2][512];        // fp32 [g][ h | c ]
  __shared__ __align__(16) _Float16 hcH[2][512];    // fp16 mirror for dot2
  __shared__ __align__(16) float qpart[4][2][256];  // [jk][g][e]
  __shared__ __align__(16) float Qs[2][256];        // exp(2q)
  __shared__ __align__(16) float spart[2][2][256];  // [eh][g][t]
  __shared__ __align__(16) float ealpha[2][256];
  __shared__ __align__(16) float gpart[2][2][1024]; // [kh][g][j]
  __shared__ __align__(16) _Float16 PhL[2][12][256][8]; // 96KB step-invariant Ph2 stage; epilogue cpart alias
  __shared__ __align__(16) float w2l[256];
  __shared__ __align__(16) float Wihl[1024];
  __shared__ __align__(16) float bl[1024];
  __shared__ __align__(16) float xfL[2][256];
  __shared__ __align__(16) float yhL[2][256];
  __shared__ float redA[8], redB[8];

  const int tid = threadIdx.x;
  const int b0 = blockIdx.x * 2;
  const int hi = tid >> 8;     // 0..3, wave-uniform
  const int lo = tid & 255;
  const int wv = tid >> 6, lane = tid & 63;

  // ---- init + one-time Ph2 stage (12 chunks x 2 rows = 96KB) ----
  ((float*)hc)[tid] = 0.f;
  ((_Float16*)hcH)[tid] = (_Float16)0.f;
  if (tid < 256) w2l[tid] = w2g[tid];
  Wihl[tid & 1023] = Wih[tid & 1023];
  bl[tid] = bih[tid] + bhh[tid];
  if (tid < 512) {
    int gi = tid >> 8, ti = tid & 255;
    xfL[gi][ti] = xf[(size_t)(b0 + gi) * 256 + ti];
    yhL[gi][ti] = y_hist[(size_t)(b0 + gi) * 256 + ti];
  }
  {
    half8* phl8 = reinterpret_cast<half8*>(&PhL[0][0][0][0]);
    const half8* ph8 = reinterpret_cast<const half8*>(Ph2);
#pragma unroll
    for (int u = 0; u < 6; ++u) {
      int slot = u * 1024 + tid;          // 0..6143
      int g = slot >= 3072;
      int rem = slot - g * 3072;
      int ci = rem >> 8;                  // 0..11
      int t = rem & 255;
      int cc = (ci < 6) ? (2 * ci) : (16 + 2 * (ci - 6));  // staged chunk ids
      phl8[slot] = ph8[((size_t)(b0 + g) * 32 + cc) * 256 + t];
    }
  }
  __syncthreads();
  float w2sum = 0.f;
  for (int e2 = 0; e2 < 256; ++e2) w2sum += w2l[e2];
  const float fcb0 = fcb[0];
  const float fcwy = fcw[256];

  // per-thread role constants
  // q phase: thread = (jk = hi, e = lo), k in [jk*128, +128)  [wave-uniform jk]
  const half8* wq = reinterpret_cast<const half8*>(w1hcQ) + tid;  // chunk c: wq[c*1024]
  // gates: thread = (jo = lo, kh = hi&1, jp = hi>>1); outputs {jp*2,jp*2+1}, k in [kh*128,+128)
  const int kh = hi & 1, jp = hi >> 1;
  const half8* wg = reinterpret_cast<const half8*>(whhG) + (size_t)kh * 16384 + jp * 512 + lo;
  // scores: thread = (g = tid>>9, eh = (tid>>8)&1, t = lo), e in [eh*128, +128)
  const int gs = tid >> 9, eh = (tid >> 8) & 1;
  const half8* prow = reinterpret_cast<const half8*>(Ph2) +
                      ((size_t)((b0 + gs) * 32 + eh * 16)) * 256 + lo;
  const half8* phlR = reinterpret_cast<const half8*>(&PhL[0][0][0][0]) +
                      (gs * 12 + eh * 6) * 256 + lo;
  // pointwise / softmax-combine (tid < 512)
  const int gp = (tid >> 8) & 1;

#pragma unroll 1
  for (int s = 0; s < 256; ++s) {
    // ---- phase 1: q[e] = hc . w1_hc[e,:], k-split 4 (wave-uniform), both rows ----
    float a0 = 0.f, a1 = 0.f;
    {
      const half8* hp0 = reinterpret_cast<const half8*>(&hcH[0][hi * 128]);
      const half8* hp1 = reinterpret_cast<const half8*>(&hcH[1][hi * 128]);
#pragma unroll 8
      for (int c = 0; c < 16; ++c) {
        half8 w = wq[c * 1024];
        half8 h0 = hp0[c];   // broadcast read (same addr across wave)
        half8 h1 = hp1[c];
        a0 = dot8_(w, h0, a0);
        a1 = dot8_(w, h1, a1);
      }
    }
    qpart[hi][0][lo] = a0;
    qpart[hi][1][lo] = a1;
    __syncthreads();  // B1

    // ---- phase 2: Qs (tid<512) + gates GEMV h@Whh (all threads, both rows) ----
    if (tid < 512) {
      float qv = qpart[0][gp][lo] + qpart[1][gp][lo] + qpart[2][gp][lo] + qpart[3][gp][lo];
      Qs[gp][lo] = __expf(2.f * qv);
    }
    float ac00 = 0.f, ac01 = 0.f, ac10 = 0.f, ac11 = 0.f;  // [js][row]
    {
      const half8* hg0 = reinterpret_cast<const half8*>(&hcH[0][kh * 128]);
      const half8* hg1 = reinterpret_cast<const half8*>(&hcH[1][kh * 128]);
#pragma unroll 4
      for (int c = 0; c < 16; ++c) {
        half8 h0 = hg0[c];   // broadcast
        half8 h1 = hg1[c];
        half8 w0 = wg[c * 1024];
        half8 w1v = wg[c * 1024 + 256];
        ac00 = dot8_(w0, h0, ac00);  ac10 = dot8_(w0, h1, ac10);
        ac01 = dot8_(w1v, h0, ac01); ac11 = dot8_(w1v, h1, ac11);
      }
    }
    gpart[kh][0][(jp * 2 + 0) * 256 + lo] = ac00;
    gpart[kh][0][(jp * 2 + 1) * 256 + lo] = ac01;
    gpart[kh][1][(jp * 2 + 0) * 256 + lo] = ac10;
    gpart[kh][1][(jp * 2 + 1) * 256 + lo] = ac11;
    __syncthreads();  // B2

    // ---- phase 3: scores, e-split 2; 6 chunks LDS + 10 streamed ----
    float sacc0 = 0.f, sacc1 = 0.f;
    {
      const float4* q4 = reinterpret_cast<const float4*>(&Qs[gs][eh * 128]);
      const float4* w4 = reinterpret_cast<const float4*>(&w2l[eh * 128]);
      // issue the 10 global loads first (plain; latency hides under LDS math)
      half8 s1 = prow[1 * 256];
      half8 s3 = prow[3 * 256];
      half8 s5 = prow[5 * 256];
      half8 s7 = prow[7 * 256];
      half8 s9 = prow[9 * 256];
      half8 s11 = prow[11 * 256];
      half8 s12 = prow[12 * 256];
      half8 s13 = prow[13 * 256];
      half8 s14 = prow[14 * 256];
      half8 s15 = prow[15 * 256];
      // staged chunks from LDS (zero latency)
      { half8 l0 = phlR[0 * 256];  SC1(l0, 0) }
      { half8 l2 = phlR[1 * 256];  SC1(l2, 2) }
      { half8 l4 = phlR[2 * 256];  SC1(l4, 4) }
      { half8 l6 = phlR[3 * 256];  SC1(l6, 6) }
      { half8 l8 = phlR[4 * 256];  SC1(l8, 8) }
      { half8 la = phlR[5 * 256];  SC1(la, 10) }
      // streamed chunks
      SC1(s1, 1)  SC1(s3, 3)  SC1(s5, 5)  SC1(s7, 7)  SC1(s9, 9)
      SC1(s11, 11) SC1(s12, 12) SC1(s13, 13) SC1(s14, 14) SC1(s15, 15)
    }
    spart[eh][gs][lo] = sacc0 + sacc1;
    __syncthreads();  // B3

    // ---- phase 4: combine + softmax reduce (tid < 512) ----
    if (tid < 512) {
      float sc = w2sum - 2.f * (spart[0][gp][lo] + spart[1][gp][lo]);
      float ea = __expf(sc);  // no max-sub: |sc| <= ~21, fp32-safe
      ealpha[gp][lo] = ea;
      float ef = ea * xfL[gp][lo];
      float es = ea;
#pragma unroll
      for (int off = 32; off > 0; off >>= 1) {
        es += __shfl_xor(es, off);
        ef += __shfl_xor(ef, off);
      }
      if (lane == 0) { redA[wv] = es; redB[wv] = ef; }
    }
    __syncthreads();  // B4

    // ---- phase 5: LSTM pointwise (tid < 512) ----
    if (tid < 512) {
      float es = (gp == 0) ? (redA[0] + redA[1] + redA[2] + redA[3])
                           : (redA[4] + redA[5] + redA[6] + redA[7]);
      float ef = (gp == 0) ? (redB[0] + redB[1] + redB[2] + redB[3])
                           : (redB[4] + redB[5] + redB[6] + redB[7]);
      float yt = ef * rcpf_(es) + fmaf(yhL[gp][s], fcwy, fcb0);
      float gi = fmaf(yt, Wihl[lo], bl[lo]);
      float gf = fmaf(yt, Wihl[256 + lo], bl[256 + lo]);
      float gc = fmaf(yt, Wihl[512 + lo], bl[512 + lo]);
      float go = fmaf(yt, Wihl[768 + lo], bl[768 + lo]);
      gi += gpart[0][gp][lo] + gpart[1][gp][lo];
      gf += gpart[0][gp][256 + lo] + gpart[1][gp][256 + lo];
      gc += gpart[0][gp][512 + lo] + gpart[1][gp][512 + lo];
      go += gpart[0][gp][768 + lo] + gpart[1][gp][768 + lo];
      float iv = sigmoidf_(gi), fv = sigmoidf_(gf), gv = tanhf_(gc), ov = sigmoidf_(go);
      float cold = hc[gp][256 + lo];
      float cn = fmaf(fv, cold, iv * gv);
      float hn = ov * tanhf_(cn);
      hc[gp][lo] = hn;
      hc[gp][256 + lo] = cn;
      hcH[gp][lo] = (_Float16)hn;
      hcH[gp][256 + lo] = (_Float16)cn;
    }
    __syncthreads();  // B5
  }

  // ---- epilogue: context from step-255 ealpha, then out = [h|ctx].fcf ----
  // read last-step softmax sums BEFORE redA/redB get reused
  const float rsA = rcpf_(redA[0] + redA[1] + redA[2] + redA[3]);
  const float rsB = rcpf_(redA[4] + redA[5] + redA[6] + redA[7]);

  float* cpartF = reinterpret_cast<float*>(&PhL[0][0][0][0]);  // 32KB alias in 96KB stage
  {
    const int gc = tid >> 9, t16 = (tid >> 5) & 15, l5 = tid & 31;
    const half8* xrow = reinterpret_cast<const half8*>(xh) +
                        ((size_t)(b0 + gc) * 256 + t16 * 16) * 32 + l5;
    float acx[8];
#pragma unroll
    for (int m = 0; m < 8; ++m) acx[m] = 0.f;
#pragma unroll 4
    for (int it = 0; it < 16; ++it) {
      float al = ealpha[gc][t16 * 16 + it];
      half8 xv = xrow[it * 32];
#pragma unroll
      for (int m = 0; m < 8; ++m) acx[m] = fmaf(al, (float)xv[m], acx[m]);
    }
    float* dst = &cpartF[((gc * 16 + t16) * 256) + l5 * 8];
    *reinterpret_cast<float4*>(dst) = *reinterpret_cast<float4*>(&acx[0]);
    *reinterpret_cast<float4*>(dst + 4) = *reinterpret_cast<float4*>(&acx[4]);
  }
  __syncthreads();

  if (tid < 512) {
    float cv = 0.f;
#pragma unroll
    for (int u = 0; u < 16; ++u) cv += cpartF[((gp * 16 + u) * 256) + lo];
    cv *= (gp == 0) ? rsA : rsB;
    float hval = hc[gp][lo];
    float p0 = hval * fcfw[lo] + cv * fcfw[256 + lo];
    float p1 = hval * fcfw[512 + lo] + cv * fcfw[768 + lo];
#pragma unroll
    for (int off = 32; off > 0; off >>= 1) {
      p0 += __shfl_xor(p0, off);
      p1 += __shfl_xor(p1, off);
    }
    if (lane == 0) { redA[wv] = p0; redB[wv] = p1; }
  }
  __syncthreads();
  if (tid < 4) {
    int g2 = tid >> 1, o = tid & 1;
    const float* r = (o == 0) ? redA : redB;
    float v = fcfb[o] + r[g2 * 4 + 0] + r[g2 * 4 + 1] + r[g2 * 4 + 2] + r[g2 * 4 + 3];
    out[(b0 + g2) * 2 + o] = v;
  }
}

extern "C" void kernel_launch(void* const* d_in, const int* in_sizes, int n_in,
                              void* d_out, int out_size, void* d_ws, size_t ws_size,
                              hipStream_t stream) {
  (void)in_sizes; (void)n_in; (void)out_size; (void)ws_size;
  const float* x    = (const float*)d_in[0];
  const float* yh   = (const float*)d_in[1];
  const float* w1   = (const float*)d_in[2];
  const float* b1   = (const float*)d_in[3];
  const float* w2   = (const float*)d_in[4];
  /* d_in[5] attn_b2: softmax-invariant, unused */
  const float* Wih  = (const float*)d_in[6];
  const float* Whh  = (const float*)d_in[7];
  const float* bih  = (const float*)d_in[8];
  const float* bhh  = (const float*)d_in[9];
  const float* fcw  = (const float*)d_in[10];
  const float* fcb  = (const float*)d_in[11];
  const float* fcfw = (const float*)d_in[12];
  const float* fcfb = (const float*)d_in[13];
  float* out = (float*)d_out;

  char* ws = (char*)d_ws;
  _Float16* Ph2   = (_Float16*)(ws);                      // 67108864 B
  _Float16* xh    = (_Float16*)(ws + (size_t)67108864);   // 67108864 B
  float*    wT    = (float*)   (ws + (size_t)134217728);  // 262144 B
  _Float16* w1hcQ = (_Float16*)(ws + (size_t)134479872);  // 262144 B
  _Float16* whhG  = (_Float16*)(ws + (size_t)134742016);  // 524288 B
  float*    xf    = (float*)   (ws + (size_t)135266304);  // 524288 B
  // total: 135790592 B (~129.5 MB)

  k_prep_wT   <<<256,   256, 0, stream>>>(w1, wT);
  k_prep_xh   <<<32768, 256, 0, stream>>>(x, xh);
  k_prep_w1hcQ<<<512,   256, 0, stream>>>(w1, w1hcQ);
  k_prep_whhG <<<1024,  256, 0, stream>>>(Whh, whhG);
  k_xf        <<<8192,  256, 0, stream>>>(x, fcw, xf);
  k_encp      <<<8192,  256, 0, stream>>>(x, wT, b1, Ph2);
  k_scan      <<<256,  1024, 0, stream>>>(Ph2, xh, w1hcQ, whhG, xf, yh, w2, Wih,
                                          bih, bhh, fcw, fcb, fcfw, fcfb, out);
}

// Round 12
// 3721.813 us; speedup vs baseline: 2.5512x; 1.0957x over previous
//
#include <hip/hip_runtime.h>
#include <cstdint>
#include <cstddef>

// Decoder (DA-RNN): B=512, T=256, E=D=256.
// Round 14: base = R13 (best, ~3990us k_scan, L2-resident, FETCH ~120MB).
// Structural change: merge q-phase into gates-phase so the w1hc (256KB) and
// whh (512KB) L2 streams are CONCURRENT instead of serialized:
//  - q: 512 threads, lane-PAIR k-split (kh=tid&1, e=tid>>1, both rows):
//    combine is one __shfl_xor(a,1) in-wave -> Qs written directly.
//    No qpart, no combine barrier.
//  - gates: 512 threads (tid>=512), 2 j's x full k each, 4 acc chains ->
//    COMPLETE gate values into gfull[2][1024]. No gpart combine.
//  - step: [A: q||gates] B1 [B: scores] B2 [C: combine+reduce] B3
//          [D: pointwise] B4  -> 4 barriers (was 5).
//  - freed LDS (qpart 8KB, gpart-8KB) -> stage 14 Ph2 chunk-ids (112KB);
//    scores stream 9 (was 10). LDS ~147KB.
// No register state crosses any barrier (6x-confirmed allocator constraint).

typedef _Float16 half8 __attribute__((ext_vector_type(8)));
typedef _Float16 half4v __attribute__((ext_vector_type(4)));
typedef _Float16 half2v __attribute__((ext_vector_type(2)));

__device__ __forceinline__ float rcpf_(float x) { return __builtin_amdgcn_rcpf(x); }
__device__ __forceinline__ float sigmoidf_(float x) { return rcpf_(1.f + __expf(-x)); }
__device__ __forceinline__ float tanhf_(float x) { return 1.f - 2.f * rcpf_(1.f + __expf(2.f * x)); }

#if defined(__has_builtin)
#if __has_builtin(__builtin_amdgcn_fdot2)
#define HAS_FDOT2 1
#endif
#endif
#ifndef HAS_FDOT2
#define HAS_FDOT2 0
#endif

__device__ __forceinline__ float fdot2_(half2v a, half2v b, float c) {
#if HAS_FDOT2
  return __builtin_amdgcn_fdot2(a, b, c, false);
#else
  return fmaf((float)a[0], (float)b[0], fmaf((float)a[1], (float)b[1], c));
#endif
}

__device__ __forceinline__ float dot8_(half8 w, half8 h, float acc) {
  acc = fdot2_(__builtin_shufflevector(w, w, 0, 1), __builtin_shufflevector(h, h, 0, 1), acc);
  acc = fdot2_(__builtin_shufflevector(w, w, 2, 3), __builtin_shufflevector(h, h, 2, 3), acc);
  acc = fdot2_(__builtin_shufflevector(w, w, 4, 5), __builtin_shufflevector(h, h, 4, 5), acc);
  acc = fdot2_(__builtin_shufflevector(w, w, 6, 7), __builtin_shufflevector(h, h, 6, 7), acc);
  return acc;
}

// ---------------- prep kernels ----------------

// wT[e*256+f] = attn_w1[f*768 + 512 + e]   (transposed w1_enc, fp32)
__global__ void k_prep_wT(const float* __restrict__ w1, float* __restrict__ wT) {
  int id = blockIdx.x * 256 + threadIdx.x;
  int e = id >> 8, f = id & 255;
  wT[id] = w1[f * 768 + 512 + e];
}

// x -> fp16 (4 elems/thread), layout unchanged [b][t][e]
__global__ void k_prep_xh(const float* __restrict__ x, _Float16* __restrict__ xh) {
  int id = blockIdx.x * 256 + threadIdx.x;
  float4 v = reinterpret_cast<const float4*>(x)[id];
  half4v h;
  h[0] = (_Float16)v.x; h[1] = (_Float16)v.y; h[2] = (_Float16)v.z; h[3] = (_Float16)v.w;
  reinterpret_cast<half4v*>(xh)[id] = h;
}

// w1hcP2[(c*512 + e*2 + kh)*8 + m] = w1[e*768 + kh*256 + c*8 + m], c in [0,32)
// (k_scan q-thread tid = e*2+kh reads chunk c at half8 index c*512 + tid)
__global__ void k_prep_w1hcQ(const float* __restrict__ w1, _Float16* __restrict__ o) {
  int id = blockIdx.x * 256 + threadIdx.x;  // 131072 total
  int m = id & 7, lane = (id >> 3) & 511, c = id >> 12;
  int e = lane >> 1, kh = lane & 1;
  o[id] = (_Float16)w1[e * 768 + kh * 256 + c * 8 + m];
}

// whhJ[(c*1024 + j)*8 + m] = Whh[j*256 + c*8 + m], c in [0,32)
// (gates thread u handles j in {u, u+512}, both lane-consecutive)
__global__ void k_prep_whhG(const float* __restrict__ whh, _Float16* __restrict__ o) {
  int id = blockIdx.x * 256 + threadIdx.x;  // 262144 total
  int m = id & 7, j = (id >> 3) & 1023, c = id >> 13;
  o[id] = (_Float16)whh[j * 256 + c * 8 + m];
}

// xf[b*256+t] = sum_e x[b,t,e] * fcw[e]   (fp32)
__global__ __launch_bounds__(256) void k_xf(const float* __restrict__ x,
                                            const float* __restrict__ fcw,
                                            float* __restrict__ xf) {
  __shared__ float xl[16][256];
  __shared__ float fw[256];
  __shared__ float part[16][17];
  const int tid = threadIdx.x;
  const int m0 = blockIdx.x * 16;
  fw[tid] = fcw[tid];
#pragma unroll
  for (int r = 0; r < 16; ++r) xl[r][tid] = x[(size_t)(m0 + r) * 256 + tid];
  __syncthreads();
  int r = tid >> 4, p = tid & 15;
  float s = 0.f;
#pragma unroll
  for (int u = 0; u < 16; ++u) s = fmaf(xl[r][p * 16 + u], fw[p * 16 + u], s);
  part[r][p] = s;
  __syncthreads();
  if (tid < 16) {
    float t = 0.f;
#pragma unroll
    for (int p2 = 0; p2 < 16; ++p2) t += part[tid][p2];
    xf[m0 + tid] = t;
  }
}

// enc_proj GEMM + bias, store P=exp(2*encp) fp16 in layout [b][e/8][t][e%8]
__global__ __launch_bounds__(256) void k_encp(const float* __restrict__ x,
                                              const float* __restrict__ wT,
                                              const float* __restrict__ b1,
                                              _Float16* __restrict__ Ph2) {
  __shared__ __align__(16) float xl[16][256];
  const int tid = threadIdx.x;
  const int m0 = blockIdx.x * 16;
#pragma unroll
  for (int r = 0; r < 16; ++r) xl[r][tid] = x[(size_t)(m0 + r) * 256 + tid];
  __syncthreads();
  float acc[16];
#pragma unroll
  for (int r = 0; r < 16; ++r) acc[r] = 0.f;
  for (int e = 0; e < 256; e += 4) {
    float w0 = wT[(e + 0) * 256 + tid];
    float w1_ = wT[(e + 1) * 256 + tid];
    float w2_ = wT[(e + 2) * 256 + tid];
    float w3_ = wT[(e + 3) * 256 + tid];
#pragma unroll
    for (int r = 0; r < 16; ++r) {
      float4 xv = *reinterpret_cast<const float4*>(&xl[r][e]);
      acc[r] = fmaf(xv.x, w0, acc[r]);
      acc[r] = fmaf(xv.y, w1_, acc[r]);
      acc[r] = fmaf(xv.z, w2_, acc[r]);
      acc[r] = fmaf(xv.w, w3_, acc[r]);
    }
  }
  float bb = b1[tid];
  const int e = tid;
#pragma unroll
  for (int r = 0; r < 16; ++r) {
    int m = m0 + r, b = m >> 8, t = m & 255;
    float p = __expf(2.f * (acc[r] + bb));
    Ph2[((size_t)(b * 32 + (e >> 3)) * 256 + t) * 8 + (e & 7)] = (_Float16)p;
  }
}

#define SC1(pv, c) { \
  float4 qa = q4[2*(c)], wa = w4[2*(c)]; \
  sacc0 = fmaf(wa.x, rcpf_(fmaf((float)pv[0], qa.x, 1.f)), sacc0); \
  sacc1 = fmaf(wa.y, rcpf_(fmaf((float)pv[1], qa.y, 1.f)), sacc1); \
  sacc0 = fmaf(wa.z, rcpf_(fmaf((float)pv[2], qa.z, 1.f)), sacc0); \
  sacc1 = fmaf(wa.w, rcpf_(fmaf((float)pv[3], qa.w, 1.f)), sacc1); \
  float4 qb = q4[2*(c)+1], wb = w4[2*(c)+1]; \
  sacc0 = fmaf(wb.x, rcpf_(fmaf((float)pv[4], qb.x, 1.f)), sacc0); \
  sacc1 = fmaf(wb.y, rcpf_(fmaf((float)pv[5], qb.y, 1.f)), sacc1); \
  sacc0 = fmaf(wb.z, rcpf_(fmaf((float)pv[6], qb.z, 1.f)), sacc0); \
  sacc1 = fmaf(wb.w, rcpf_(fmaf((float)pv[7], qb.w, 1.f)), sacc1); }

// ---------------- the scan ----------------
// grid 256 x 1024 threads; wg owns 2 batch rows; 256 steps; 4 barriers/step.
__global__ __launch_bounds__(1024, 4) void k_scan(
    const _Float16* __restrict__ Ph2, const _Float16* __restrict__ xh,
    const _Float16* __restrict__ w1hcQ, const _Float16* __restrict__ whhG,
    const float* __restrict__ xf, const float* __restrict__ y_hist,
    const float* __restrict__ w2g, const float* __restrict__ Wih,
    const float* __restrict__ bih, const float* __restrict__ bhh,
    const float* __restrict__ fcw, const float* __restrict__ fcb,
    const float* __restrict__ fcfw, const float* __restrict__ fcfb,
    float* __restrict__ out) {
  __shared__ __align__(16) float hc[2][512];        // fp32 [g][ h | c ]
  __shared__ __align__(16) _Float16 hcH[2][512];    // fp16 mirror for dot2
  __shared__ __align__(16) float Qs[2][256];        // exp(2q)
  __shared__ __align__(16) float spart[2][2][256];  // [eh][g][t]
  __shared__ __align__(16) float ealpha[2][256];
  __shared__ __align__(16) float gfull[2][1024];    // complete gate GEMV values
  __shared__ __align__(16) _Float16 PhL[2][14][256][8]; // 112KB step-invariant Ph2 stage; epilogue cpart alias
  __shared__ __align__(16) float w2l[256];
  __shared__ __align__(16) float Wihl[1024];
  __shared__ __align__(16) float bl[1024];
  __shared__ __align__(16) float xfL[2][256];
  __shared__ __align__(16) float yhL[2][256];
  __shared__ float redA[8], redB[8];

  const int tid = threadIdx.x;
  const int b0 = blockIdx.x * 2;
  const int lo = tid & 255;
  const int wv = tid >> 6, lane = tid & 63;

  // ---- init + one-time Ph2 stage (14 chunk-ids x 2 rows = 112KB) ----
  ((float*)hc)[tid] = 0.f;
  ((_Float16*)hcH)[tid] = (_Float16)0.f;
  if (tid < 256) w2l[tid] = w2g[tid];
  Wihl[tid & 1023] = Wih[tid & 1023];
  bl[tid] = bih[tid] + bhh[tid];
  if (tid < 512) {
    int gi = tid >> 8, ti = tid & 255;
    xfL[gi][ti] = xf[(size_t)(b0 + gi) * 256 + ti];
    yhL[gi][ti] = y_hist[(size_t)(b0 + gi) * 256 + ti];
  }
  {
    half8* phl8 = reinterpret_cast<half8*>(&PhL[0][0][0][0]);
    const half8* ph8 = reinterpret_cast<const half8*>(Ph2);
#pragma unroll
    for (int u2 = 0; u2 < 7; ++u2) {
      int slot = u2 * 1024 + tid;         // 0..7167
      int g = slot >= 3584;
      int rem = slot - g * 3584;
      int ci = rem >> 8;                  // 0..13
      int t = rem & 255;
      int cc = (ci < 7) ? (2 * ci) : (16 + 2 * (ci - 7));  // staged chunk ids
      phl8[slot] = ph8[((size_t)(b0 + g) * 32 + cc) * 256 + t];
    }
  }
  __syncthreads();
  float w2sum = 0.f;
  for (int e2 = 0; e2 < 256; ++e2) w2sum += w2l[e2];
  const float fcb0 = fcb[0];
  const float fcwy = fcw[256];

  // per-thread role constants
  // phase A q (tid<512): e = tid>>1, kh = tid&1 (lane-pair k-split), both rows
  const half8* wq2 = reinterpret_cast<const half8*>(w1hcQ) + tid;  // chunk c: wq2[c*512]
  const int khq = tid & 1;
  // phase A gates (tid>=512): u = tid-512; j in {u, u+512}, full k
  const int ug = (tid - 512) & 511;
  const half8* wgJ = reinterpret_cast<const half8*>(whhG) + ug;    // j0: [c*1024], j1: [c*1024+512]
  // scores: thread = (gs = tid>>9, eh = (tid>>8)&1, t = lo), e in [eh*128, +128)
  const int gs = tid >> 9, eh = (tid >> 8) & 1;
  const half8* prow = reinterpret_cast<const half8*>(Ph2) +
                      ((size_t)((b0 + gs) * 32 + eh * 16)) * 256 + lo;
  const half8* phlR = reinterpret_cast<const half8*>(&PhL[0][0][0][0]) +
                      (gs * 14 + eh * 7) * 256 + lo;
  // pointwise / softmax-combine (tid < 512)
  const int gp = (tid >> 8) & 1;

#pragma unroll 1
  for (int s = 0; s < 256; ++s) {
    // ---- phase A: q (lane-pair, both rows) || gates (full-k, 2 j's, both rows) ----
    if (tid < 512) {
      float a0 = 0.f, a1 = 0.f;
      const half8* hp0 = reinterpret_cast<const half8*>(&hcH[0][khq * 256]);
      const half8* hp1 = reinterpret_cast<const half8*>(&hcH[1][khq * 256]);
#pragma unroll 8
      for (int c = 0; c < 32; ++c) {
        half8 w = wq2[c * 512];
        a0 = dot8_(w, hp0[c], a0);   // 2 addrs/wave (kh) -> 2-way, free
        a1 = dot8_(w, hp1[c], a1);
      }
      a0 += __shfl_xor(a0, 1);       // lane-pair combine: q complete
      a1 += __shfl_xor(a1, 1);
      if (khq == 0) {
        int e = tid >> 1;
        Qs[0][e] = __expf(2.f * a0);
        Qs[1][e] = __expf(2.f * a1);
      }
    } else {
      float ac00 = 0.f, ac01 = 0.f, ac10 = 0.f, ac11 = 0.f;  // [jslot][row]
      const half8* hg0 = reinterpret_cast<const half8*>(&hcH[0][0]);
      const half8* hg1 = reinterpret_cast<const half8*>(&hcH[1][0]);
#pragma unroll 4
      for (int c = 0; c < 32; ++c) {
        half8 h0 = hg0[c];   // broadcast
        half8 h1 = hg1[c];
        half8 w0 = wgJ[c * 1024];
        half8 w1v = wgJ[c * 1024 + 512];
        ac00 = dot8_(w0, h0, ac00);  ac01 = dot8_(w0, h1, ac01);
        ac10 = dot8_(w1v, h0, ac10); ac11 = dot8_(w1v, h1, ac11);
      }
      gfull[0][ug] = ac00;
      gfull[1][ug] = ac01;
      gfull[0][ug + 512] = ac10;
      gfull[1][ug + 512] = ac11;
    }
    __syncthreads();  // B1

    // ---- phase B: scores, e-split 2; 7 chunks LDS + 9 streamed ----
    float sacc0 = 0.f, sacc1 = 0.f;
    {
      const float4* q4 = reinterpret_cast<const float4*>(&Qs[gs][eh * 128]);
      const float4* w4 = reinterpret_cast<const float4*>(&w2l[eh * 128]);
      // issue the 9 global loads first (latency hides under LDS math)
      half8 s1 = prow[1 * 256];
      half8 s3 = prow[3 * 256];
      half8 s5 = prow[5 * 256];
      half8 s7 = prow[7 * 256];
      half8 s9 = prow[9 * 256];
      half8 s11 = prow[11 * 256];
      half8 s13 = prow[13 * 256];
      half8 s14 = prow[14 * 256];
      half8 s15 = prow[15 * 256];
      // staged chunks from LDS (zero latency)
      { half8 l0 = phlR[0 * 256];  SC1(l0, 0) }
      { half8 l2 = phlR[1 * 256];  SC1(l2, 2) }
      { half8 l4 = phlR[2 * 256];  SC1(l4, 4) }
      { half8 l6 = phlR[3 * 256];  SC1(l6, 6) }
      { half8 l8 = phlR[4 * 256];  SC1(l8, 8) }
      { half8 la = phlR[5 * 256];  SC1(la, 10) }
      { half8 lc = phlR[6 * 256];  SC1(lc, 12) }
      // streamed chunks
      SC1(s1, 1)  SC1(s3, 3)  SC1(s5, 5)  SC1(s7, 7)  SC1(s9, 9)
      SC1(s11, 11) SC1(s13, 13) SC1(s14, 14) SC1(s15, 15)
    }
    spart[eh][gs][lo] = sacc0 + sacc1;
    __syncthreads();  // B2

    // ---- phase C: combine + softmax reduce (tid < 512) ----
    if (tid < 512) {
      float sc = w2sum - 2.f * (spart[0][gp][lo] + spart[1][gp][lo]);
      float ea = __expf(sc);  // no max-sub: |sc| <= ~21, fp32-safe
      ealpha[gp][lo] = ea;
      float ef = ea * xfL[gp][lo];
      float es = ea;
#pragma unroll
      for (int off = 32; off > 0; off >>= 1) {
        es += __shfl_xor(es, off);
        ef += __shfl_xor(ef, off);
      }
      if (lane == 0) { redA[wv] = es; redB[wv] = ef; }
    }
    __syncthreads();  // B3

    // ---- phase D: LSTM pointwise (tid < 512) ----
    if (tid < 512) {
      float es = (gp == 0) ? (redA[0] + redA[1] + redA[2] + redA[3])
                           : (redA[4] + redA[5] + redA[6] + redA[7]);
      float ef = (gp == 0) ? (redB[0] + redB[1] + redB[2] + redB[3])
                           : (redB[4] + redB[5] + redB[6] + redB[7]);
      float yt = ef * rcpf_(es) + fmaf(yhL[gp][s], fcwy, fcb0);
      float gi = fmaf(yt, Wihl[lo], bl[lo]) + gfull[gp][lo];
      float gf = fmaf(yt, Wihl[256 + lo], bl[256 + lo]) + gfull[gp][256 + lo];
      float gc = fmaf(yt, Wihl[512 + lo], bl[512 + lo]) + gfull[gp][512 + lo];
      float go = fmaf(yt, Wihl[768 + lo], bl[768 + lo]) + gfull[gp][768 + lo];
      float iv = sigmoidf_(gi), fv = sigmoidf_(gf), gv = tanhf_(gc), ov = sigmoidf_(go);
      float cold = hc[gp][256 + lo];
      float cn = fmaf(fv, cold, iv * gv);
      float hn = ov * tanhf_(cn);
      hc[gp][lo] = hn;
      hc[gp][256 + lo] = cn;
      hcH[gp][lo] = (_Float16)hn;
      hcH[gp][256 + lo] = (_Float16)cn;
    }
    __syncthreads();  // B4
  }

  // ---- epilogue: context from step-255 ealpha, then out = [h|ctx].fcf ----
  // read last-step softmax sums BEFORE redA/redB get reused
  const float rsA = rcpf_(redA[0] + redA[1] + redA[2] + redA[3]);
  const float rsB = rcpf_(redA[4] + redA[5] + redA[6] + redA[7]);

  float* cpartF = reinterpret_cast<float*>(&PhL[0][0][0][0]);  // 32KB alias in 112KB stage
  {
    const int gc = tid >> 9, t16 = (tid >> 5) & 15, l5 = tid & 31;
    const half8* xrow = reinterpret_cast<const half8*>(xh) +
                        ((size_t)(b0 + gc) * 256 + t16 * 16) * 32 + l5;
    float acx[8];
#pragma unroll
    for (int m = 0; m < 8; ++m) acx[m] = 0.f;
#pragma unroll 4
    for (int it = 0; it < 16; ++it) {
      float al = ealpha[gc][t16 * 16 + it];
      half8 xv = xrow[it * 32];
#pragma unroll
      for (int m = 0; m < 8; ++m) acx[m] = fmaf(al, (float)xv[m], acx[m]);
    }
    float* dst = &cpartF[((gc * 16 + t16) * 256) + l5 * 8];
    *reinterpret_cast<float4*>(dst) = *reinterpret_cast<float4*>(&acx[0]);
    *reinterpret_cast<float4*>(dst + 4) = *reinterpret_cast<float4*>(&acx[4]);
  }
  __syncthreads();

  if (tid < 512) {
    float cv = 0.f;
#pragma unroll
    for (int u = 0; u < 16; ++u) cv += cpartF[((gp * 16 + u) * 256) + lo];
    cv *= (gp == 0) ? rsA : rsB;
    float hval = hc[gp][lo];
    float p0 = hval * fcfw[lo] + cv * fcfw[256 + lo];
    float p1 = hval * fcfw[512 + lo] + cv * fcfw[768 + lo];
#pragma unroll
    for (int off = 32; off > 0; off >>= 1) {
      p0 += __shfl_xor(p0, off);
      p1 += __shfl_xor(p1, off);
    }
    if (lane == 0) { redA[wv] = p0; redB[wv] = p1; }
  }
  __syncthreads();
  if (tid < 4) {
    int g2 = tid >> 1, o = tid & 1;
    const float* r = (o == 0) ? redA : redB;
    float v = fcfb[o] + r[g2 * 4 + 0] + r[g2 * 4 + 1] + r[g2 * 4 + 2] + r[g2 * 4 + 3];
    out[(b0 + g2) * 2 + o] = v;
  }
}

extern "C" void kernel_launch(void* const* d_in, const int* in_sizes, int n_in,
                              void* d_out, int out_size, void* d_ws, size_t ws_size,
                              hipStream_t stream) {
  (void)in_sizes; (void)n_in; (void)out_size; (void)ws_size;
  const float* x    = (const float*)d_in[0];
  const float* yh   = (const float*)d_in[1];
  const float* w1   = (const float*)d_in[2];
  const float* b1   = (const float*)d_in[3];
  const float* w2   = (const float*)d_in[4];
  /* d_in[5] attn_b2: softmax-invariant, unused */
  const float* Wih  = (const float*)d_in[6];
  const float* Whh  = (const float*)d_in[7];
  const float* bih  = (const float*)d_in[8];
  const float* bhh  = (const float*)d_in[9];
  const float* fcw  = (const float*)d_in[10];
  const float* fcb  = (const float*)d_in[11];
  const float* fcfw = (const float*)d_in[12];
  const float* fcfb = (const float*)d_in[13];
  float* out = (float*)d_out;

  char* ws = (char*)d_ws;
  _Float16* Ph2   = (_Float16*)(ws);                      // 67108864 B
  _Float16* xh    = (_Float16*)(ws + (size_t)67108864);   // 67108864 B
  float*    wT    = (float*)   (ws + (size_t)134217728);  // 262144 B
  _Float16* w1hcQ = (_Float16*)(ws + (size_t)134479872);  // 262144 B
  _Float16* whhG  = (_Float16*)(ws + (size_t)134742016);  // 524288 B
  float*    xf    = (float*)   (ws + (size_t)135266304);  // 524288 B
  // total: 135790592 B (~129.5 MB)

  k_prep_wT   <<<256,   256, 0, stream>>>(w1, wT);
  k_prep_xh   <<<32768, 256, 0, stream>>>(x, xh);
  k_prep_w1hcQ<<<512,   256, 0, stream>>>(w1, w1hcQ);
  k_prep_whhG <<<1024,  256, 0, stream>>>(Whh, whhG);
  k_xf        <<<8192,  256, 0, stream>>>(x, fcw, xf);
  k_encp      <<<8192,  256, 0, stream>>>(x, wT, b1, Ph2);
  k_scan      <<<256,  1024, 0, stream>>>(Ph2, xh, w1hcQ, whhG, xf, yh, w2, Wih,
                                          bih, bhh, fcw, fcb, fcfw, fcfb, out);
}